// Round 3
// baseline (3071.155 us; speedup 1.0000x reference)
//
#include <hip/hip_runtime.h>

constexpr int N_NODES = 100000;
constexpr int N_EDGES = 3200000;
constexpr int D = 64;

__global__ __launch_bounds__(256) void k_edge_bias(
    const float* __restrict__ ew, const int* __restrict__ dst,
    const float* __restrict__ a3, float* __restrict__ edge_sums) {
  int e = blockIdx.x * 256 + threadIdx.x;
  if (e >= N_EDGES) return;
  float v = a3[0] * ew[e];
  v = fmaxf(v, 0.0f);
  atomicAdd(&edge_sums[dst[e]], v);
}

__global__ __launch_bounds__(256) void k_bias(
    const float* __restrict__ edge_sums, const int* __restrict__ labels,
    const float* __restrict__ a2, const float* __restrict__ a4,
    float* __restrict__ bias) {
  int n = blockIdx.x * 256 + threadIdx.x;
  if (n >= N_NODES) return;
  bias[n] = a2[0] * edge_sums[n] + a4[0] * (float)labels[n];
}

// One 64-lane wave per edge; lane = embedding dim.
__global__ __launch_bounds__(256) void k_scatter(
    const float* __restrict__ x, const int* __restrict__ src,
    const int* __restrict__ dst, float* __restrict__ neigh) {
  long long t = (long long)blockIdx.x * 256 + threadIdx.x;
  int e = (int)(t >> 6);
  int lane = (int)(t & 63);
  if (e >= N_EDGES) return;
  int s = src[e];
  int d = dst[e];
  float v = x[s * D + lane];
  atomicAdd(&neigh[d * D + lane], v);
}

__global__ __launch_bounds__(256) void k_relu(
    const float4* __restrict__ neigh, const float* __restrict__ bias,
    const float* __restrict__ a1, float4* __restrict__ xout) {
  int t = blockIdx.x * 256 + threadIdx.x;  // over N_NODES*16 float4s
  if (t >= N_NODES * (D / 4)) return;
  int n = t >> 4;
  float al = a1[0];
  float b = bias[n];
  float4 v = neigh[t];
  float4 r;
  r.x = fmaxf(al * v.x + b, 0.0f);
  r.y = fmaxf(al * v.y + b, 0.0f);
  r.z = fmaxf(al * v.z + b, 0.0f);
  r.w = fmaxf(al * v.w + b, 0.0f);
  xout[t] = r;
}

extern "C" void kernel_launch(void* const* d_in, const int* in_sizes, int n_in,
                              void* d_out, int out_size, void* d_ws, size_t ws_size,
                              hipStream_t stream) {
  const float* x0     = (const float*)d_in[0];
  const float* ew     = (const float*)d_in[1];
  const float* a1     = (const float*)d_in[2];
  const float* a2     = (const float*)d_in[3];
  const float* a3     = (const float*)d_in[4];
  const float* a4     = (const float*)d_in[5];
  const int*   esrc   = (const int*)d_in[6];
  const int*   edst   = (const int*)d_in[7];
  const int*   labels = (const int*)d_in[8];
  float* out = (float*)d_out;

  char* ws = (char*)d_ws;
  float* neigh     = (float*)ws;                                   // N*D floats
  float* edge_sums = (float*)(ws + (size_t)N_NODES * D * sizeof(float));
  float* bias      = edge_sums + N_NODES;

  // bias = a2 * segment_sum(relu(a3*w), dst) + a4 * labels  (iteration-invariant)
  hipMemsetAsync(edge_sums, 0, N_NODES * sizeof(float), stream);
  k_edge_bias<<<(N_EDGES + 255) / 256, 256, 0, stream>>>(ew, edst, a3, edge_sums);
  k_bias<<<(N_NODES + 255) / 256, 256, 0, stream>>>(edge_sums, labels, a2, a4, bias);

  const float* xin = x0;
  for (int it = 0; it < 4; ++it) {  // num_iterations = 4 per setup_inputs
    hipMemsetAsync(neigh, 0, (size_t)N_NODES * D * sizeof(float), stream);
    long long total_threads = (long long)N_EDGES * 64;
    k_scatter<<<(int)(total_threads / 256), 256, 0, stream>>>(xin, esrc, edst, neigh);
    k_relu<<<(N_NODES * (D / 4) + 255) / 256, 256, 0, stream>>>(
        (const float4*)neigh, bias, a1, (float4*)out);
    xin = out;
  }
}

// Round 4
// 1730.607 us; speedup vs baseline: 1.7746x; 1.7746x over previous
//
#include <hip/hip_runtime.h>

constexpr int N_NODES = 100000;
constexpr int N_EDGES = 3200000;
constexpr int D = 64;

// ============================ CSR build =================================

// One pass over edges: degree histogram + bias edge-sum (both tiny atomics).
__global__ __launch_bounds__(256) void k_hist_bias(
    const float* __restrict__ ew, const int* __restrict__ dst,
    const float* __restrict__ a3,
    int* __restrict__ deg_cursor, float* __restrict__ edge_sums) {
  int e = blockIdx.x * 256 + threadIdx.x;
  if (e >= N_EDGES) return;
  int d = dst[e];
  atomicAdd(&deg_cursor[d], 1);
  float v = fmaxf(a3[0] * ew[e], 0.0f);
  atomicAdd(&edge_sums[d], v);
}

// Single-block chunked exclusive scan over N; also emits cursor=row_start and
// the fused iteration-invariant bias = a2*edge_sums + a4*labels.
__global__ __launch_bounds__(256) void k_scan_bias(
    int* __restrict__ deg_cursor,      // in: deg, out: cursor (=row_start)
    int* __restrict__ row_start,       // out: [N+1]
    const float* __restrict__ edge_sums,
    const int* __restrict__ labels,
    const float* __restrict__ a2, const float* __restrict__ a4,
    float* __restrict__ bias) {
  __shared__ int ssum[256];
  const int t = threadIdx.x;
  const int CH = (N_NODES + 255) / 256;  // 391
  int lo = t * CH;
  int hi = lo + CH; if (hi > N_NODES) hi = N_NODES;
  int s = 0;
  for (int i = lo; i < hi; ++i) s += deg_cursor[i];
  ssum[t] = s;
  __syncthreads();
  for (int off = 1; off < 256; off <<= 1) {   // Hillis-Steele inclusive scan
    int v = (t >= off) ? ssum[t - off] : 0;
    __syncthreads();
    ssum[t] += v;
    __syncthreads();
  }
  int base = (t == 0) ? 0 : ssum[t - 1];
  float c2 = a2[0], c4 = a4[0];
  for (int i = lo; i < hi; ++i) {
    int d = deg_cursor[i];
    row_start[i] = base;
    deg_cursor[i] = base;                       // cursor for counting sort
    bias[i] = c2 * edge_sums[i] + c4 * (float)labels[i];
    base += d;
  }
  if (t == 255) row_start[N_NODES] = base;
}

// Counting sort: col[] = src indices grouped by dst.
__global__ __launch_bounds__(256) void k_sort(
    const int* __restrict__ src, const int* __restrict__ dst,
    int* __restrict__ cursor, int* __restrict__ col) {
  int e = blockIdx.x * 256 + threadIdx.x;
  if (e >= N_EDGES) return;
  int pos = atomicAdd(&cursor[dst[e]], 1);
  col[pos] = src[e];
}

// ====================== pull iteration (no atomics) =====================
// One wave per node. 4 edge-slots (sub) x 16 lanes (float4 over D=64).
__global__ __launch_bounds__(256) void k_pull(
    const float4* __restrict__ x,
    const int* __restrict__ row_start,
    const int* __restrict__ col,
    const float* __restrict__ bias,
    const float* __restrict__ a1,
    float4* __restrict__ xout) {
  int node = (blockIdx.x * 256 + threadIdx.x) >> 6;
  if (node >= N_NODES) return;
  int lane = threadIdx.x & 63;
  int sub = lane >> 4;     // which edge slot (4-way MLP)
  int l16 = lane & 15;     // which float4 of the 64-dim row
  int beg = row_start[node], end = row_start[node + 1];
  float ax = 0.f, ay = 0.f, az = 0.f, aw = 0.f;
  for (int j = beg + sub; j < end; j += 4) {
    int s = col[j];
    float4 v = x[s * 16 + l16];
    ax += v.x; ay += v.y; az += v.z; aw += v.w;
  }
  // reduce the 4 edge slots (lanes l16, 16+l16, 32+l16, 48+l16)
  ax += __shfl_xor(ax, 16); ay += __shfl_xor(ay, 16);
  az += __shfl_xor(az, 16); aw += __shfl_xor(aw, 16);
  ax += __shfl_xor(ax, 32); ay += __shfl_xor(ay, 32);
  az += __shfl_xor(az, 32); aw += __shfl_xor(aw, 32);
  if (sub == 0) {
    float al = a1[0], b = bias[node];
    float4 r;
    r.x = fmaxf(fmaf(al, ax, b), 0.f);
    r.y = fmaxf(fmaf(al, ay, b), 0.f);
    r.z = fmaxf(fmaf(al, az, b), 0.f);
    r.w = fmaxf(fmaf(al, aw, b), 0.f);
    xout[node * 16 + l16] = r;
  }
}

// ===================== fallback (round-0 atomic path) ===================

__global__ __launch_bounds__(256) void k_bias_only(
    const float* __restrict__ edge_sums, const int* __restrict__ labels,
    const float* __restrict__ a2, const float* __restrict__ a4,
    float* __restrict__ bias) {
  int n = blockIdx.x * 256 + threadIdx.x;
  if (n >= N_NODES) return;
  bias[n] = a2[0] * edge_sums[n] + a4[0] * (float)labels[n];
}

__global__ __launch_bounds__(256) void k_scatter(
    const float* __restrict__ x, const int* __restrict__ src,
    const int* __restrict__ dst, float* __restrict__ neigh) {
  long long t = (long long)blockIdx.x * 256 + threadIdx.x;
  int e = (int)(t >> 6);
  int lane = (int)(t & 63);
  if (e >= N_EDGES) return;
  float v = x[src[e] * D + lane];
  atomicAdd(&neigh[dst[e] * D + lane], v);
}

__global__ __launch_bounds__(256) void k_relu(
    const float4* __restrict__ neigh, const float* __restrict__ bias,
    const float* __restrict__ a1, float4* __restrict__ xout) {
  int t = blockIdx.x * 256 + threadIdx.x;
  if (t >= N_NODES * (D / 4)) return;
  int n = t >> 4;
  float al = a1[0], b = bias[n];
  float4 v = neigh[t];
  float4 r;
  r.x = fmaxf(al * v.x + b, 0.f);
  r.y = fmaxf(al * v.y + b, 0.f);
  r.z = fmaxf(al * v.z + b, 0.f);
  r.w = fmaxf(al * v.w + b, 0.f);
  xout[t] = r;
}

// ============================== launch ==================================

extern "C" void kernel_launch(void* const* d_in, const int* in_sizes, int n_in,
                              void* d_out, int out_size, void* d_ws, size_t ws_size,
                              hipStream_t stream) {
  const float* x0     = (const float*)d_in[0];
  const float* ew     = (const float*)d_in[1];
  const float* a1     = (const float*)d_in[2];
  const float* a2     = (const float*)d_in[3];
  const float* a3     = (const float*)d_in[4];
  const float* a4     = (const float*)d_in[5];
  const int*   esrc   = (const int*)d_in[6];
  const int*   edst   = (const int*)d_in[7];
  const int*   labels = (const int*)d_in[8];
  float* out = (float*)d_out;

  char* ws = (char*)d_ws;
  // CSR-path workspace layout (≈40.0 MB)
  size_t off = 0;
  int*   cursor    = (int*)(ws + off);   off += (size_t)N_NODES * 4;
  int*   row_start = (int*)(ws + off);   off += (size_t)(N_NODES + 1) * 4;
  float* edge_sums = (float*)(ws + off); off += (size_t)N_NODES * 4;
  float* bias      = (float*)(ws + off); off += (size_t)N_NODES * 4;
  int*   col       = (int*)(ws + off);   off += (size_t)N_EDGES * 4;
  float* xbuf      = (float*)(ws + off); off += (size_t)N_NODES * D * 4;
  const size_t need_csr = off;

  const int EBLK = (N_EDGES + 255) / 256;

  if (ws_size >= need_csr) {
    // ---- CSR build (once per call) ----
    hipMemsetAsync(cursor, 0, (size_t)N_NODES * 4, stream);
    hipMemsetAsync(edge_sums, 0, (size_t)N_NODES * 4, stream);
    k_hist_bias<<<EBLK, 256, 0, stream>>>(ew, edst, a3, cursor, edge_sums);
    k_scan_bias<<<1, 256, 0, stream>>>(cursor, row_start, edge_sums,
                                       labels, a2, a4, bias);
    k_sort<<<EBLK, 256, 0, stream>>>(esrc, edst, cursor, col);

    // ---- 4 pull iterations, ping-pong x0 -> xbuf -> out -> xbuf -> out
    const int PBLK = (N_NODES * 64 + 255) / 256;
    const float4* xin = (const float4*)x0;
    float4* dsts[4] = {(float4*)xbuf, (float4*)out, (float4*)xbuf, (float4*)out};
    for (int it = 0; it < 4; ++it) {
      k_pull<<<PBLK, 256, 0, stream>>>(xin, row_start, col, bias, a1, dsts[it]);
      xin = dsts[it];
    }
  } else {
    // ---- fallback: atomic push path (round-0) ----
    float* neigh  = (float*)ws;
    float* esums  = (float*)(ws + (size_t)N_NODES * D * 4);
    float* fbias  = esums + N_NODES;
    hipMemsetAsync(esums, 0, N_NODES * 4, stream);
    k_hist_bias<<<EBLK, 256, 0, stream>>>(ew, edst, a3, (int*)fbias /*dummy*/, esums);
    k_bias_only<<<(N_NODES + 255) / 256, 256, 0, stream>>>(esums, labels, a2, a4, fbias);
    const float* xin = x0;
    for (int it = 0; it < 4; ++it) {
      hipMemsetAsync(neigh, 0, (size_t)N_NODES * D * 4, stream);
      long long tt = (long long)N_EDGES * 64;
      k_scatter<<<(int)(tt / 256), 256, 0, stream>>>(xin, esrc, edst, neigh);
      k_relu<<<(N_NODES * (D / 4) + 255) / 256, 256, 0, stream>>>(
          (const float4*)neigh, fbias, a1, (float4*)out);
      xin = out;
    }
  }
}

// Round 5
// 1183.876 us; speedup vs baseline: 2.5942x; 1.4618x over previous
//
#include <hip/hip_runtime.h>

constexpr int N_NODES = 100000;
constexpr int N_EDGES = 3200000;
constexpr int D = 64;
constexpr int SCAN_CHUNK = 1024;
constexpr int N_SBLK = (N_NODES + SCAN_CHUNK - 1) / SCAN_CHUNK;  // 98

// ============================ CSR build =================================

// One pass over edges: degree histogram + bias edge-sum (small atomics).
__global__ __launch_bounds__(256) void k_hist_bias(
    const float* __restrict__ ew, const int* __restrict__ dst,
    const float* __restrict__ a3,
    int* __restrict__ deg_cursor, float* __restrict__ edge_sums) {
  int e = blockIdx.x * 256 + threadIdx.x;
  if (e >= N_EDGES) return;
  int d = dst[e];
  atomicAdd(&deg_cursor[d], 1);
  float v = fmaxf(a3[0] * ew[e], 0.0f);
  atomicAdd(&edge_sums[d], v);
}

// Two-level scan, stage 1: per-block (1024-node chunk) degree sums.
__global__ __launch_bounds__(256) void k_partial(
    const int* __restrict__ deg, int* __restrict__ partials) {
  __shared__ int red[256];
  int t = threadIdx.x;
  int base = blockIdx.x * SCAN_CHUNK + t * 4;
  int s = 0;
#pragma unroll
  for (int k = 0; k < 4; ++k) {
    int i = base + k;
    if (i < N_NODES) s += deg[i];
  }
  red[t] = s;
  __syncthreads();
  for (int off = 128; off > 0; off >>= 1) {
    if (t < off) red[t] += red[t + off];
    __syncthreads();
  }
  if (t == 0) partials[blockIdx.x] = red[0];
}

// Stage 2: exclusive scan of the 98 partials (single tiny block).
__global__ __launch_bounds__(128) void k_scan_small(int* __restrict__ partials) {
  __shared__ int sh[128];
  int t = threadIdx.x;
  int v = (t < N_SBLK) ? partials[t] : 0;
  sh[t] = v;
  __syncthreads();
  for (int off = 1; off < 128; off <<= 1) {
    int u = (t >= off) ? sh[t - off] : 0;
    __syncthreads();
    sh[t] += u;
    __syncthreads();
  }
  if (t < N_SBLK) partials[t] = sh[t] - v;  // exclusive
}

// Stage 3: block-local scan + apply. Emits row_start, sort cursor, bias.
__global__ __launch_bounds__(256) void k_scan_apply(
    int* __restrict__ deg_cursor,        // in: deg, out: cursor (=row_start)
    int* __restrict__ row_start,         // out: [N+1]
    const int* __restrict__ partials,
    const float* __restrict__ edge_sums,
    const int* __restrict__ labels,
    const float* __restrict__ a2, const float* __restrict__ a4,
    float* __restrict__ bias) {
  __shared__ int sh[256];
  int b = blockIdx.x, t = threadIdx.x;
  int base = b * SCAN_CHUNK + t * 4;
  int d[4];
  int s = 0;
#pragma unroll
  for (int k = 0; k < 4; ++k) {
    int i = base + k;
    d[k] = (i < N_NODES) ? deg_cursor[i] : 0;
    s += d[k];
  }
  sh[t] = s;
  __syncthreads();
  for (int off = 1; off < 256; off <<= 1) {  // Hillis-Steele inclusive
    int u = (t >= off) ? sh[t - off] : 0;
    __syncthreads();
    sh[t] += u;
    __syncthreads();
  }
  int run = partials[b] + sh[t] - s;  // exclusive prefix for this thread
  float c2 = a2[0], c4 = a4[0];
#pragma unroll
  for (int k = 0; k < 4; ++k) {
    int i = base + k;
    if (i < N_NODES) {
      row_start[i] = run;
      deg_cursor[i] = run;
      bias[i] = c2 * edge_sums[i] + c4 * (float)labels[i];
      run += d[k];
    }
  }
  if (b == 0 && t == 0) row_start[N_NODES] = N_EDGES;
}

// Counting sort: col[] = src indices grouped by dst.
__global__ __launch_bounds__(256) void k_sort(
    const int* __restrict__ src, const int* __restrict__ dst,
    int* __restrict__ cursor, int* __restrict__ col) {
  int e = blockIdx.x * 256 + threadIdx.x;
  if (e >= N_EDGES) return;
  int pos = atomicAdd(&cursor[dst[e]], 1);
  col[pos] = src[e];
}

// ====================== pull iteration (no atomics) =====================
// One wave per node. 4 edge-slots (sub) x 16 lanes (float4 over D=64).
__global__ __launch_bounds__(256) void k_pull(
    const float4* __restrict__ x,
    const int* __restrict__ row_start,
    const int* __restrict__ col,
    const float* __restrict__ bias,
    const float* __restrict__ a1,
    float4* __restrict__ xout) {
  int node = (blockIdx.x * 256 + threadIdx.x) >> 6;
  if (node >= N_NODES) return;
  int lane = threadIdx.x & 63;
  int sub = lane >> 4;     // which edge slot
  int l16 = lane & 15;     // which float4 of the 64-dim row
  int beg = row_start[node], end = row_start[node + 1];
  float ax = 0.f, ay = 0.f, az = 0.f, aw = 0.f;
  for (int j = beg + sub; j < end; j += 4) {
    int s = col[j];
    float4 v = x[s * 16 + l16];
    ax += v.x; ay += v.y; az += v.z; aw += v.w;
  }
  ax += __shfl_xor(ax, 16); ay += __shfl_xor(ay, 16);
  az += __shfl_xor(az, 16); aw += __shfl_xor(aw, 16);
  ax += __shfl_xor(ax, 32); ay += __shfl_xor(ay, 32);
  az += __shfl_xor(az, 32); aw += __shfl_xor(aw, 32);
  if (sub == 0) {
    float al = a1[0], b = bias[node];
    float4 r;
    r.x = fmaxf(fmaf(al, ax, b), 0.f);
    r.y = fmaxf(fmaf(al, ay, b), 0.f);
    r.z = fmaxf(fmaf(al, az, b), 0.f);
    r.w = fmaxf(fmaf(al, aw, b), 0.f);
    xout[node * 16 + l16] = r;
  }
}

// ===================== fallback (atomic push path) ======================

__global__ __launch_bounds__(256) void k_bias_only(
    const float* __restrict__ edge_sums, const int* __restrict__ labels,
    const float* __restrict__ a2, const float* __restrict__ a4,
    float* __restrict__ bias) {
  int n = blockIdx.x * 256 + threadIdx.x;
  if (n >= N_NODES) return;
  bias[n] = a2[0] * edge_sums[n] + a4[0] * (float)labels[n];
}

__global__ __launch_bounds__(256) void k_scatter(
    const float* __restrict__ x, const int* __restrict__ src,
    const int* __restrict__ dst, float* __restrict__ neigh) {
  long long t = (long long)blockIdx.x * 256 + threadIdx.x;
  int e = (int)(t >> 6);
  int lane = (int)(t & 63);
  if (e >= N_EDGES) return;
  float v = x[src[e] * D + lane];
  atomicAdd(&neigh[dst[e] * D + lane], v);
}

__global__ __launch_bounds__(256) void k_relu(
    const float4* __restrict__ neigh, const float* __restrict__ bias,
    const float* __restrict__ a1, float4* __restrict__ xout) {
  int t = blockIdx.x * 256 + threadIdx.x;
  if (t >= N_NODES * (D / 4)) return;
  int n = t >> 4;
  float al = a1[0], b = bias[n];
  float4 v = neigh[t];
  float4 r;
  r.x = fmaxf(al * v.x + b, 0.f);
  r.y = fmaxf(al * v.y + b, 0.f);
  r.z = fmaxf(al * v.z + b, 0.f);
  r.w = fmaxf(al * v.w + b, 0.f);
  xout[t] = r;
}

// ============================== launch ==================================

extern "C" void kernel_launch(void* const* d_in, const int* in_sizes, int n_in,
                              void* d_out, int out_size, void* d_ws, size_t ws_size,
                              hipStream_t stream) {
  const float* x0     = (const float*)d_in[0];
  const float* ew     = (const float*)d_in[1];
  const float* a1     = (const float*)d_in[2];
  const float* a2     = (const float*)d_in[3];
  const float* a3     = (const float*)d_in[4];
  const float* a4     = (const float*)d_in[5];
  const int*   esrc   = (const int*)d_in[6];
  const int*   edst   = (const int*)d_in[7];
  const int*   labels = (const int*)d_in[8];
  float* out = (float*)d_out;

  char* ws = (char*)d_ws;
  size_t off = 0;
  int*   cursor    = (int*)(ws + off);   off += (size_t)N_NODES * 4;
  int*   row_start = (int*)(ws + off);   off += (size_t)(N_NODES + 1) * 4;
  float* edge_sums = (float*)(ws + off); off += (size_t)N_NODES * 4;
  float* bias      = (float*)(ws + off); off += (size_t)N_NODES * 4;
  int*   partials  = (int*)(ws + off);   off += 128 * 4;
  int*   col       = (int*)(ws + off);   off += (size_t)N_EDGES * 4;
  float* xbuf      = (float*)(ws + off); off += (size_t)N_NODES * D * 4;
  const size_t need_csr = off;

  const int EBLK = (N_EDGES + 255) / 256;

  if (ws_size >= need_csr) {
    // ---- CSR build (once per call) ----
    hipMemsetAsync(cursor, 0, (size_t)N_NODES * 4, stream);
    hipMemsetAsync(edge_sums, 0, (size_t)N_NODES * 4, stream);
    k_hist_bias<<<EBLK, 256, 0, stream>>>(ew, edst, a3, cursor, edge_sums);
    k_partial<<<N_SBLK, 256, 0, stream>>>(cursor, partials);
    k_scan_small<<<1, 128, 0, stream>>>(partials);
    k_scan_apply<<<N_SBLK, 256, 0, stream>>>(cursor, row_start, partials,
                                             edge_sums, labels, a2, a4, bias);
    k_sort<<<EBLK, 256, 0, stream>>>(esrc, edst, cursor, col);

    // ---- 4 pull iterations, ping-pong x0 -> xbuf -> out -> xbuf -> out
    const int PBLK = (N_NODES * 64 + 255) / 256;
    const float4* xin = (const float4*)x0;
    float4* dsts[4] = {(float4*)xbuf, (float4*)out, (float4*)xbuf, (float4*)out};
    for (int it = 0; it < 4; ++it) {
      k_pull<<<PBLK, 256, 0, stream>>>(xin, row_start, col, bias, a1, dsts[it]);
      xin = dsts[it];
    }
  } else {
    // ---- fallback: atomic push path ----
    float* neigh  = (float*)ws;
    float* esums  = (float*)(ws + (size_t)N_NODES * D * 4);
    float* fbias  = esums + N_NODES;
    int*   dummy  = (int*)(fbias + N_NODES);
    hipMemsetAsync(esums, 0, N_NODES * 4, stream);
    hipMemsetAsync(dummy, 0, N_NODES * 4, stream);
    k_hist_bias<<<EBLK, 256, 0, stream>>>(ew, edst, a3, dummy, esums);
    k_bias_only<<<(N_NODES + 255) / 256, 256, 0, stream>>>(esums, labels, a2, a4, fbias);
    const float* xin = x0;
    for (int it = 0; it < 4; ++it) {
      hipMemsetAsync(neigh, 0, (size_t)N_NODES * D * 4, stream);
      long long tt = (long long)N_EDGES * 64;
      k_scatter<<<(int)(tt / 256), 256, 0, stream>>>(xin, esrc, edst, neigh);
      k_relu<<<(N_NODES * (D / 4) + 255) / 256, 256, 0, stream>>>(
          (const float4*)neigh, fbias, a1, (float4*)out);
      xin = out;
    }
  }
}

// Round 8
// 891.932 us; speedup vs baseline: 3.4433x; 1.3273x over previous
//
#include <hip/hip_runtime.h>

constexpr int N_NODES = 100000;
constexpr int N_EDGES = 3200000;
constexpr int D = 64;
constexpr int SCAN_CHUNK = 1024;
constexpr int N_SBLK = (N_NODES + SCAN_CHUNK - 1) / SCAN_CHUNK;  // 98

// ---------- bf16 helpers (manual RNE; no NaN/Inf in this workload) ----------
__device__ __forceinline__ float bf2f(unsigned short u) {
  union { unsigned int i; float f; } c; c.i = ((unsigned int)u) << 16; return c.f;
}
__device__ __forceinline__ unsigned short f2bf(float f) {
  union { float f; unsigned int i; } c; c.f = f;
  unsigned int b = c.i;
  return (unsigned short)((b + 0x7FFFu + ((b >> 16) & 1u)) >> 16);
}

// ============================ CSR build =================================

// Degree histogram only (one int atomic per edge).
__global__ __launch_bounds__(256) void k_hist(
    const int* __restrict__ dst, int* __restrict__ deg_cursor) {
  int e = blockIdx.x * 256 + threadIdx.x;
  if (e >= N_EDGES) return;
  atomicAdd(&deg_cursor[dst[e]], 1);
}

// Two-level scan, stage 1: per-1024-node-chunk degree sums.
__global__ __launch_bounds__(256) void k_partial(
    const int* __restrict__ deg, int* __restrict__ partials) {
  __shared__ int red[256];
  int t = threadIdx.x;
  int base = blockIdx.x * SCAN_CHUNK + t * 4;
  int s = 0;
#pragma unroll
  for (int k = 0; k < 4; ++k) {
    int i = base + k;
    if (i < N_NODES) s += deg[i];
  }
  red[t] = s;
  __syncthreads();
  for (int off = 128; off > 0; off >>= 1) {
    if (t < off) red[t] += red[t + off];
    __syncthreads();
  }
  if (t == 0) partials[blockIdx.x] = red[0];
}

// Stage 2: exclusive scan of the 98 partials.
__global__ __launch_bounds__(128) void k_scan_small(int* __restrict__ partials) {
  __shared__ int sh[128];
  int t = threadIdx.x;
  int v = (t < N_SBLK) ? partials[t] : 0;
  sh[t] = v;
  __syncthreads();
  for (int off = 1; off < 128; off <<= 1) {
    int u = (t >= off) ? sh[t - off] : 0;
    __syncthreads();
    sh[t] += u;
    __syncthreads();
  }
  if (t < N_SBLK) partials[t] = sh[t] - v;  // exclusive
}

// Stage 3: block-local scan + apply. Emits row_start and sort cursor.
__global__ __launch_bounds__(256) void k_scan_apply(
    int* __restrict__ deg_cursor,        // in: deg, out: cursor (=row_start)
    int* __restrict__ row_start,         // out: [N+1]
    const int* __restrict__ partials) {
  __shared__ int sh[256];
  int b = blockIdx.x, t = threadIdx.x;
  int base = b * SCAN_CHUNK + t * 4;
  int d[4];
  int s = 0;
#pragma unroll
  for (int k = 0; k < 4; ++k) {
    int i = base + k;
    d[k] = (i < N_NODES) ? deg_cursor[i] : 0;
    s += d[k];
  }
  sh[t] = s;
  __syncthreads();
  for (int off = 1; off < 256; off <<= 1) {  // Hillis-Steele inclusive
    int u = (t >= off) ? sh[t - off] : 0;
    __syncthreads();
    sh[t] += u;
    __syncthreads();
  }
  int run = partials[b] + sh[t] - s;  // exclusive prefix for this thread
#pragma unroll
  for (int k = 0; k < 4; ++k) {
    int i = base + k;
    if (i < N_NODES) {
      row_start[i] = run;
      deg_cursor[i] = run;
      run += d[k];
    }
  }
  if (b == 0 && t == 0) row_start[N_NODES] = N_EDGES;
}

// Counting sort: col[] = src grouped by dst; wsorted[] = relu(a3*w) grouped.
__global__ __launch_bounds__(256) void k_sort(
    const int* __restrict__ src, const int* __restrict__ dst,
    const float* __restrict__ ew, const float* __restrict__ a3,
    int* __restrict__ cursor, int* __restrict__ col,
    float* __restrict__ wsorted) {
  int e = blockIdx.x * 256 + threadIdx.x;
  if (e >= N_EDGES) return;
  int pos = atomicAdd(&cursor[dst[e]], 1);
  col[pos] = src[e];
  wsorted[pos] = fmaxf(a3[0] * ew[e], 0.0f);
}

// bias[n] = a2 * sum(wsorted[row]) + a4 * labels[n]
__global__ __launch_bounds__(256) void k_bias_csr(
    const int* __restrict__ row_start, const float* __restrict__ wsorted,
    const int* __restrict__ labels,
    const float* __restrict__ a2, const float* __restrict__ a4,
    float* __restrict__ bias) {
  int n = blockIdx.x * 256 + threadIdx.x;
  if (n >= N_NODES) return;
  int beg = row_start[n], end = row_start[n + 1];
  float s = 0.f;
  for (int j = beg; j < end; ++j) s += wsorted[j];
  bias[n] = a2[0] * s + a4[0] * (float)labels[n];
}

// f32 -> bf16 conversion of the initial x.
__global__ __launch_bounds__(256) void k_cvt(
    const float4* __restrict__ xin, ushort4* __restrict__ xout) {
  int t = blockIdx.x * 256 + threadIdx.x;  // over N*D/4 groups
  if (t >= N_NODES * (D / 4)) return;
  float4 v = xin[t];
  ushort4 r;
  r.x = f2bf(v.x); r.y = f2bf(v.y); r.z = f2bf(v.z); r.w = f2bf(v.w);
  xout[t] = r;
}

// ====================== pull iteration (no atomics) =====================
// One wave per node; 4 edge slots x 16 lanes; bf16 rows (128B each).
template <int WRITE_BF16>
__global__ __launch_bounds__(256) void k_pull(
    const ushort4* __restrict__ x,
    const int* __restrict__ row_start,
    const int* __restrict__ col,
    const float* __restrict__ bias,
    const float* __restrict__ a1,
    float4* __restrict__ outf, ushort4* __restrict__ outb) {
  int node = (blockIdx.x * 256 + threadIdx.x) >> 6;
  if (node >= N_NODES) return;
  int lane = threadIdx.x & 63;
  int sub = lane >> 4;     // edge slot
  int l16 = lane & 15;     // which 4-dim group of the 64-dim row
  int beg = row_start[node], end = row_start[node + 1];
  float ax = 0.f, ay = 0.f, az = 0.f, aw = 0.f;
  for (int j = beg + sub; j < end; j += 4) {
    int s = col[j];
    ushort4 v = x[s * 16 + l16];
    ax += bf2f(v.x); ay += bf2f(v.y); az += bf2f(v.z); aw += bf2f(v.w);
  }
  ax += __shfl_xor(ax, 16); ay += __shfl_xor(ay, 16);
  az += __shfl_xor(az, 16); aw += __shfl_xor(aw, 16);
  ax += __shfl_xor(ax, 32); ay += __shfl_xor(ay, 32);
  az += __shfl_xor(az, 32); aw += __shfl_xor(aw, 32);
  if (sub == 0) {
    float al = a1[0], b = bias[node];
    float rx = fmaxf(fmaf(al, ax, b), 0.f);
    float ry = fmaxf(fmaf(al, ay, b), 0.f);
    float rz = fmaxf(fmaf(al, az, b), 0.f);
    float rw = fmaxf(fmaf(al, aw, b), 0.f);
    if (WRITE_BF16) {
      ushort4 r;
      r.x = f2bf(rx); r.y = f2bf(ry); r.z = f2bf(rz); r.w = f2bf(rw);
      outb[node * 16 + l16] = r;
    } else {
      float4 r; r.x = rx; r.y = ry; r.z = rz; r.w = rw;
      outf[node * 16 + l16] = r;
    }
  }
}

// ===================== fallback (atomic push path) ======================

__global__ __launch_bounds__(256) void k_hist_legacy(
    const float* __restrict__ ew, const int* __restrict__ dst,
    const float* __restrict__ a3, float* __restrict__ edge_sums) {
  int e = blockIdx.x * 256 + threadIdx.x;
  if (e >= N_EDGES) return;
  atomicAdd(&edge_sums[dst[e]], fmaxf(a3[0] * ew[e], 0.0f));
}

__global__ __launch_bounds__(256) void k_bias_only(
    const float* __restrict__ edge_sums, const int* __restrict__ labels,
    const float* __restrict__ a2, const float* __restrict__ a4,
    float* __restrict__ bias) {
  int n = blockIdx.x * 256 + threadIdx.x;
  if (n >= N_NODES) return;
  bias[n] = a2[0] * edge_sums[n] + a4[0] * (float)labels[n];
}

__global__ __launch_bounds__(256) void k_scatter(
    const float* __restrict__ x, const int* __restrict__ src,
    const int* __restrict__ dst, float* __restrict__ neigh) {
  long long t = (long long)blockIdx.x * 256 + threadIdx.x;
  int e = (int)(t >> 6);
  int lane = (int)(t & 63);
  if (e >= N_EDGES) return;
  atomicAdd(&neigh[dst[e] * D + lane], x[src[e] * D + lane]);
}

__global__ __launch_bounds__(256) void k_relu(
    const float4* __restrict__ neigh, const float* __restrict__ bias,
    const float* __restrict__ a1, float4* __restrict__ xout) {
  int t = blockIdx.x * 256 + threadIdx.x;
  if (t >= N_NODES * (D / 4)) return;
  int n = t >> 4;
  float al = a1[0], b = bias[n];
  float4 v = neigh[t];
  float4 r;
  r.x = fmaxf(al * v.x + b, 0.f);
  r.y = fmaxf(al * v.y + b, 0.f);
  r.z = fmaxf(al * v.z + b, 0.f);
  r.w = fmaxf(al * v.w + b, 0.f);
  xout[t] = r;
}

// ============================== launch ==================================

extern "C" void kernel_launch(void* const* d_in, const int* in_sizes, int n_in,
                              void* d_out, int out_size, void* d_ws, size_t ws_size,
                              hipStream_t stream) {
  const float* x0     = (const float*)d_in[0];
  const float* ew     = (const float*)d_in[1];
  const float* a1     = (const float*)d_in[2];
  const float* a2     = (const float*)d_in[3];
  const float* a3     = (const float*)d_in[4];
  const float* a4     = (const float*)d_in[5];
  const int*   esrc   = (const int*)d_in[6];
  const int*   edst   = (const int*)d_in[7];
  const int*   labels = (const int*)d_in[8];
  float* out = (float*)d_out;

  char* ws = (char*)d_ws;
  size_t off = 0;
  int*   cursor    = (int*)(ws + off);   off += (size_t)N_NODES * 4;
  int*   row_start = (int*)(ws + off);   off += (size_t)(N_NODES + 4) * 4;
  float* bias      = (float*)(ws + off); off += (size_t)N_NODES * 4;
  int*   partials  = (int*)(ws + off);   off += 128 * 4;
  int*   col       = (int*)(ws + off);   off += (size_t)N_EDGES * 4;
  ushort4* xb0     = (ushort4*)(ws + off); off += (size_t)N_NODES * D * 2;
  // xb1 aliases wsorted: wsorted (E floats = 12.8MB) is dead once k_bias_csr
  // finishes, before the first pull writes xb1 (stream-ordered).
  char* alias      = ws + off;           off += (size_t)N_EDGES * 4;  // >= N*D*2
  float*   wsorted = (float*)alias;
  ushort4* xb1     = (ushort4*)alias;
  const size_t need_csr = off;

  const int EBLK = (N_EDGES + 255) / 256;
  const int PBLK = (N_NODES * 64 + 255) / 256;
  const int CBLK = (N_NODES * (D / 4) + 255) / 256;

  if (ws_size >= need_csr) {
    // ---- CSR build (once per call) ----
    k_cvt<<<CBLK, 256, 0, stream>>>((const float4*)x0, xb0);
    hipMemsetAsync(cursor, 0, (size_t)N_NODES * 4, stream);
    k_hist<<<EBLK, 256, 0, stream>>>(edst, cursor);
    k_partial<<<N_SBLK, 256, 0, stream>>>(cursor, partials);
    k_scan_small<<<1, 128, 0, stream>>>(partials);
    k_scan_apply<<<N_SBLK, 256, 0, stream>>>(cursor, row_start, partials);
    k_sort<<<EBLK, 256, 0, stream>>>(esrc, edst, ew, a3, cursor, col, wsorted);
    k_bias_csr<<<(N_NODES + 255) / 256, 256, 0, stream>>>(
        row_start, wsorted, labels, a2, a4, bias);

    // ---- 4 pull iterations: xb0 -> xb1 -> xb0 -> xb1 -> out(f32)
    k_pull<1><<<PBLK, 256, 0, stream>>>(xb0, row_start, col, bias, a1, nullptr, xb1);
    k_pull<1><<<PBLK, 256, 0, stream>>>(xb1, row_start, col, bias, a1, nullptr, xb0);
    k_pull<1><<<PBLK, 256, 0, stream>>>(xb0, row_start, col, bias, a1, nullptr, xb1);
    k_pull<0><<<PBLK, 256, 0, stream>>>(xb1, row_start, col, bias, a1, (float4*)out, nullptr);
  } else {
    // ---- fallback: atomic push path (f32 end-to-end) ----
    float* neigh  = (float*)ws;
    float* esums  = (float*)(ws + (size_t)N_NODES * D * 4);
    float* fbias  = esums + N_NODES;
    hipMemsetAsync(esums, 0, N_NODES * 4, stream);
    k_hist_legacy<<<EBLK, 256, 0, stream>>>(ew, edst, a3, esums);
    k_bias_only<<<(N_NODES + 255) / 256, 256, 0, stream>>>(esums, labels, a2, a4, fbias);
    const float* xin = x0;
    for (int it = 0; it < 4; ++it) {
      hipMemsetAsync(neigh, 0, (size_t)N_NODES * D * 4, stream);
      long long tt = (long long)N_EDGES * 64;
      k_scatter<<<(int)(tt / 256), 256, 0, stream>>>(xin, esrc, edst, neigh);
      k_relu<<<CBLK, 256, 0, stream>>>((const float4*)neigh, fbias, a1, (float4*)out);
      xin = out;
    }
  }
}

// Round 9
// 737.646 us; speedup vs baseline: 4.1635x; 1.2092x over previous
//
#include <hip/hip_runtime.h>

constexpr int N_NODES = 100000;
constexpr int N_EDGES = 3200000;
constexpr int D = 64;
constexpr int SCAN_CHUNK = 1024;
constexpr int N_SBLK = (N_NODES + SCAN_CHUNK - 1) / SCAN_CHUNK;  // 98

// ---------- bf16 helpers (manual RNE; no NaN/Inf in this workload) ----------
__device__ __forceinline__ float bf2f(unsigned short u) {
  union { unsigned int i; float f; } c; c.i = ((unsigned int)u) << 16; return c.f;
}
__device__ __forceinline__ unsigned short f2bf(float f) {
  union { float f; unsigned int i; } c; c.f = f;
  unsigned int b = c.i;
  return (unsigned short)((b + 0x7FFFu + ((b >> 16) & 1u)) >> 16);
}

// ============================ CSR build =================================

// Histogram + rank: one atomic per edge, rank stored sequentially (coalesced).
__global__ __launch_bounds__(256) void k_hist_rank(
    const int* __restrict__ dst, int* __restrict__ deg,
    unsigned short* __restrict__ rank) {
  int e = blockIdx.x * 256 + threadIdx.x;
  if (e >= N_EDGES) return;
  rank[e] = (unsigned short)atomicAdd(&deg[dst[e]], 1);
}

// Legacy histogram (tier-B path).
__global__ __launch_bounds__(256) void k_hist(
    const int* __restrict__ dst, int* __restrict__ deg_cursor) {
  int e = blockIdx.x * 256 + threadIdx.x;
  if (e >= N_EDGES) return;
  atomicAdd(&deg_cursor[dst[e]], 1);
}

// Two-level scan, stage 1: per-1024-node-chunk degree sums.
__global__ __launch_bounds__(256) void k_partial(
    const int* __restrict__ deg, int* __restrict__ partials) {
  __shared__ int red[256];
  int t = threadIdx.x;
  int base = blockIdx.x * SCAN_CHUNK + t * 4;
  int s = 0;
#pragma unroll
  for (int k = 0; k < 4; ++k) {
    int i = base + k;
    if (i < N_NODES) s += deg[i];
  }
  red[t] = s;
  __syncthreads();
  for (int off = 128; off > 0; off >>= 1) {
    if (t < off) red[t] += red[t + off];
    __syncthreads();
  }
  if (t == 0) partials[blockIdx.x] = red[0];
}

// Stage 2: exclusive scan of the 98 partials.
__global__ __launch_bounds__(128) void k_scan_small(int* __restrict__ partials) {
  __shared__ int sh[128];
  int t = threadIdx.x;
  int v = (t < N_SBLK) ? partials[t] : 0;
  sh[t] = v;
  __syncthreads();
  for (int off = 1; off < 128; off <<= 1) {
    int u = (t >= off) ? sh[t - off] : 0;
    __syncthreads();
    sh[t] += u;
    __syncthreads();
  }
  if (t < N_SBLK) partials[t] = sh[t] - v;  // exclusive
}

// Stage 3: block-local scan + apply. Emits row_start (and cursor copy).
__global__ __launch_bounds__(256) void k_scan_apply(
    int* __restrict__ deg_cursor,        // in: deg, out: cursor (=row_start)
    int* __restrict__ row_start,         // out: [N+1]
    const int* __restrict__ partials) {
  __shared__ int sh[256];
  int b = blockIdx.x, t = threadIdx.x;
  int base = b * SCAN_CHUNK + t * 4;
  int d[4];
  int s = 0;
#pragma unroll
  for (int k = 0; k < 4; ++k) {
    int i = base + k;
    d[k] = (i < N_NODES) ? deg_cursor[i] : 0;
    s += d[k];
  }
  sh[t] = s;
  __syncthreads();
  for (int off = 1; off < 256; off <<= 1) {  // Hillis-Steele inclusive
    int u = (t >= off) ? sh[t - off] : 0;
    __syncthreads();
    sh[t] += u;
    __syncthreads();
  }
  int run = partials[b] + sh[t] - s;  // exclusive prefix for this thread
#pragma unroll
  for (int k = 0; k < 4; ++k) {
    int i = base + k;
    if (i < N_NODES) {
      row_start[i] = run;
      deg_cursor[i] = run;
      run += d[k];
    }
  }
  if (b == 0 && t == 0) row_start[N_NODES] = N_EDGES;
}

// Non-atomic scatter: pos = row_start[dst] + rank; single 8B store per edge.
__global__ __launch_bounds__(256) void k_scatter_rank(
    const int* __restrict__ src, const int* __restrict__ dst,
    const float* __restrict__ ew, const float* __restrict__ a3,
    const int* __restrict__ row_start, const unsigned short* __restrict__ rank,
    int2* __restrict__ col_w) {
  int e = blockIdx.x * 256 + threadIdx.x;
  if (e >= N_EDGES) return;
  int d = dst[e];
  int pos = row_start[d] + (int)rank[e];
  int2 v;
  v.x = src[e];
  v.y = __float_as_int(fmaxf(a3[0] * ew[e], 0.0f));
  col_w[pos] = v;
}

// bias[n] = a2 * sum(col_w[row].y) + a4 * labels[n]
__global__ __launch_bounds__(256) void k_bias_csr2(
    const int* __restrict__ row_start, const int2* __restrict__ col_w,
    const int* __restrict__ labels,
    const float* __restrict__ a2, const float* __restrict__ a4,
    float* __restrict__ bias) {
  int n = blockIdx.x * 256 + threadIdx.x;
  if (n >= N_NODES) return;
  int beg = row_start[n], end = row_start[n + 1];
  float s = 0.f;
  for (int j = beg; j < end; ++j) s += __int_as_float(col_w[j].y);
  bias[n] = a2[0] * s + a4[0] * (float)labels[n];
}

// f32 -> bf16 conversion of the initial x.
__global__ __launch_bounds__(256) void k_cvt(
    const float4* __restrict__ xin, ushort4* __restrict__ xout) {
  int t = blockIdx.x * 256 + threadIdx.x;  // over N*D/4 groups
  if (t >= N_NODES * (D / 4)) return;
  float4 v = xin[t];
  ushort4 r;
  r.x = f2bf(v.x); r.y = f2bf(v.y); r.z = f2bf(v.z); r.w = f2bf(v.w);
  xout[t] = r;
}

// ====================== pull iteration (no atomics) =====================
// One wave per node; 4 edge slots x 16 lanes; bf16 rows (128B each).
// 2-deep unrolled gather for memory-level parallelism.
template <int WRITE_BF16>
__global__ __launch_bounds__(256) void k_pull2(
    const ushort4* __restrict__ x,
    const int* __restrict__ row_start,
    const int2* __restrict__ col_w,
    const float* __restrict__ bias,
    const float* __restrict__ a1,
    float4* __restrict__ outf, ushort4* __restrict__ outb) {
  int node = (blockIdx.x * 256 + threadIdx.x) >> 6;
  if (node >= N_NODES) return;
  int lane = threadIdx.x & 63;
  int sub = lane >> 4;     // edge slot
  int l16 = lane & 15;     // which 4-dim group of the 64-dim row
  int beg = row_start[node], end = row_start[node + 1];
  float ax = 0.f, ay = 0.f, az = 0.f, aw = 0.f;
  for (int j = beg + sub; j < end; j += 8) {
    int s0 = col_w[j].x;
    int j2 = j + 4;
    int s1 = (j2 < end) ? col_w[j2].x : -1;
    ushort4 v0 = x[s0 * 16 + l16];
    ax += bf2f(v0.x); ay += bf2f(v0.y); az += bf2f(v0.z); aw += bf2f(v0.w);
    if (s1 >= 0) {
      ushort4 v1 = x[s1 * 16 + l16];
      ax += bf2f(v1.x); ay += bf2f(v1.y); az += bf2f(v1.z); aw += bf2f(v1.w);
    }
  }
  ax += __shfl_xor(ax, 16); ay += __shfl_xor(ay, 16);
  az += __shfl_xor(az, 16); aw += __shfl_xor(aw, 16);
  ax += __shfl_xor(ax, 32); ay += __shfl_xor(ay, 32);
  az += __shfl_xor(az, 32); aw += __shfl_xor(aw, 32);
  if (sub == 0) {
    float al = a1[0], b = bias[node];
    float rx = fmaxf(fmaf(al, ax, b), 0.f);
    float ry = fmaxf(fmaf(al, ay, b), 0.f);
    float rz = fmaxf(fmaf(al, az, b), 0.f);
    float rw = fmaxf(fmaf(al, aw, b), 0.f);
    if (WRITE_BF16) {
      ushort4 r;
      r.x = f2bf(rx); r.y = f2bf(ry); r.z = f2bf(rz); r.w = f2bf(rw);
      outb[node * 16 + l16] = r;
    } else {
      float4 r; r.x = rx; r.y = ry; r.z = rz; r.w = rw;
      outf[node * 16 + l16] = r;
    }
  }
}

// =================== tier-B kernels (round-8 CSR path) ==================

__global__ __launch_bounds__(256) void k_sort(
    const int* __restrict__ src, const int* __restrict__ dst,
    const float* __restrict__ ew, const float* __restrict__ a3,
    int* __restrict__ cursor, int* __restrict__ col,
    float* __restrict__ wsorted) {
  int e = blockIdx.x * 256 + threadIdx.x;
  if (e >= N_EDGES) return;
  int pos = atomicAdd(&cursor[dst[e]], 1);
  col[pos] = src[e];
  wsorted[pos] = fmaxf(a3[0] * ew[e], 0.0f);
}

__global__ __launch_bounds__(256) void k_bias_csr(
    const int* __restrict__ row_start, const float* __restrict__ wsorted,
    const int* __restrict__ labels,
    const float* __restrict__ a2, const float* __restrict__ a4,
    float* __restrict__ bias) {
  int n = blockIdx.x * 256 + threadIdx.x;
  if (n >= N_NODES) return;
  int beg = row_start[n], end = row_start[n + 1];
  float s = 0.f;
  for (int j = beg; j < end; ++j) s += wsorted[j];
  bias[n] = a2[0] * s + a4[0] * (float)labels[n];
}

template <int WRITE_BF16>
__global__ __launch_bounds__(256) void k_pull(
    const ushort4* __restrict__ x,
    const int* __restrict__ row_start,
    const int* __restrict__ col,
    const float* __restrict__ bias,
    const float* __restrict__ a1,
    float4* __restrict__ outf, ushort4* __restrict__ outb) {
  int node = (blockIdx.x * 256 + threadIdx.x) >> 6;
  if (node >= N_NODES) return;
  int lane = threadIdx.x & 63;
  int sub = lane >> 4;
  int l16 = lane & 15;
  int beg = row_start[node], end = row_start[node + 1];
  float ax = 0.f, ay = 0.f, az = 0.f, aw = 0.f;
  for (int j = beg + sub; j < end; j += 4) {
    int s = col[j];
    ushort4 v = x[s * 16 + l16];
    ax += bf2f(v.x); ay += bf2f(v.y); az += bf2f(v.z); aw += bf2f(v.w);
  }
  ax += __shfl_xor(ax, 16); ay += __shfl_xor(ay, 16);
  az += __shfl_xor(az, 16); aw += __shfl_xor(aw, 16);
  ax += __shfl_xor(ax, 32); ay += __shfl_xor(ay, 32);
  az += __shfl_xor(az, 32); aw += __shfl_xor(aw, 32);
  if (sub == 0) {
    float al = a1[0], b = bias[node];
    float rx = fmaxf(fmaf(al, ax, b), 0.f);
    float ry = fmaxf(fmaf(al, ay, b), 0.f);
    float rz = fmaxf(fmaf(al, az, b), 0.f);
    float rw = fmaxf(fmaf(al, aw, b), 0.f);
    if (WRITE_BF16) {
      ushort4 r;
      r.x = f2bf(rx); r.y = f2bf(ry); r.z = f2bf(rz); r.w = f2bf(rw);
      outb[node * 16 + l16] = r;
    } else {
      float4 r; r.x = rx; r.y = ry; r.z = rz; r.w = rw;
      outf[node * 16 + l16] = r;
    }
  }
}

// ===================== fallback (atomic push path) ======================

__global__ __launch_bounds__(256) void k_hist_legacy(
    const float* __restrict__ ew, const int* __restrict__ dst,
    const float* __restrict__ a3, float* __restrict__ edge_sums) {
  int e = blockIdx.x * 256 + threadIdx.x;
  if (e >= N_EDGES) return;
  atomicAdd(&edge_sums[dst[e]], fmaxf(a3[0] * ew[e], 0.0f));
}

__global__ __launch_bounds__(256) void k_bias_only(
    const float* __restrict__ edge_sums, const int* __restrict__ labels,
    const float* __restrict__ a2, const float* __restrict__ a4,
    float* __restrict__ bias) {
  int n = blockIdx.x * 256 + threadIdx.x;
  if (n >= N_NODES) return;
  bias[n] = a2[0] * edge_sums[n] + a4[0] * (float)labels[n];
}

__global__ __launch_bounds__(256) void k_scatter(
    const float* __restrict__ x, const int* __restrict__ src,
    const int* __restrict__ dst, float* __restrict__ neigh) {
  long long t = (long long)blockIdx.x * 256 + threadIdx.x;
  int e = (int)(t >> 6);
  int lane = (int)(t & 63);
  if (e >= N_EDGES) return;
  atomicAdd(&neigh[dst[e] * D + lane], x[src[e] * D + lane]);
}

__global__ __launch_bounds__(256) void k_relu(
    const float4* __restrict__ neigh, const float* __restrict__ bias,
    const float* __restrict__ a1, float4* __restrict__ xout) {
  int t = blockIdx.x * 256 + threadIdx.x;
  if (t >= N_NODES * (D / 4)) return;
  int n = t >> 4;
  float al = a1[0], b = bias[n];
  float4 v = neigh[t];
  float4 r;
  r.x = fmaxf(al * v.x + b, 0.f);
  r.y = fmaxf(al * v.y + b, 0.f);
  r.z = fmaxf(al * v.z + b, 0.f);
  r.w = fmaxf(al * v.w + b, 0.f);
  xout[t] = r;
}

// ============================== launch ==================================

extern "C" void kernel_launch(void* const* d_in, const int* in_sizes, int n_in,
                              void* d_out, int out_size, void* d_ws, size_t ws_size,
                              hipStream_t stream) {
  const float* x0     = (const float*)d_in[0];
  const float* ew     = (const float*)d_in[1];
  const float* a1     = (const float*)d_in[2];
  const float* a2     = (const float*)d_in[3];
  const float* a3     = (const float*)d_in[4];
  const float* a4     = (const float*)d_in[5];
  const int*   esrc   = (const int*)d_in[6];
  const int*   edst   = (const int*)d_in[7];
  const int*   labels = (const int*)d_in[8];
  float* out = (float*)d_out;

  char* ws = (char*)d_ws;
  const int EBLK = (N_EDGES + 255) / 256;
  const int PBLK = (N_NODES * 64 + 255) / 256;
  const int CBLK = (N_NODES * (D / 4) + 255) / 256;
  const int NBLK = (N_NODES + 255) / 256;

  // ---------------- tier A layout (~52.8 MB) ----------------
  size_t offA = 0;
  int*   cursorA    = (int*)(ws + offA);   offA += (size_t)N_NODES * 4;
  int*   row_startA = (int*)(ws + offA);   offA += (size_t)(N_NODES + 4) * 4;
  float* biasA      = (float*)(ws + offA); offA += (size_t)N_NODES * 4;
  int*   partialsA  = (int*)(ws + offA);   offA += 128 * 4;
  int2*  col_w      = (int2*)(ws + offA);  offA += (size_t)N_EDGES * 8;
  ushort4* xa0      = (ushort4*)(ws + offA); offA += (size_t)N_NODES * D * 2;
  // rank (ushort E = 6.4MB) aliases xa1 (12.8MB): rank dead after
  // k_scatter_rank; xa1 first written by pull #1 (stream-ordered).
  char* aliasA      = ws + offA;           offA += (size_t)N_NODES * D * 2;
  unsigned short* rank = (unsigned short*)aliasA;
  ushort4* xa1      = (ushort4*)aliasA;
  const size_t need_A = offA;

  // ---------------- tier B layout (~39.8 MB, round-8) ----------------
  size_t offB = 0;
  int*   cursorB    = (int*)(ws + offB);   offB += (size_t)N_NODES * 4;
  int*   row_startB = (int*)(ws + offB);   offB += (size_t)(N_NODES + 4) * 4;
  float* biasB      = (float*)(ws + offB); offB += (size_t)N_NODES * 4;
  int*   partialsB  = (int*)(ws + offB);   offB += 128 * 4;
  int*   colB       = (int*)(ws + offB);   offB += (size_t)N_EDGES * 4;
  ushort4* xb0      = (ushort4*)(ws + offB); offB += (size_t)N_NODES * D * 2;
  char* aliasB      = ws + offB;           offB += (size_t)N_EDGES * 4;
  float*   wsorted  = (float*)aliasB;
  ushort4* xb1      = (ushort4*)aliasB;
  const size_t need_B = offB;

  if (ws_size >= need_A) {
    // ---- tier A: rank-based CSR build, no atomic in scatter ----
    k_cvt<<<CBLK, 256, 0, stream>>>((const float4*)x0, xa0);
    hipMemsetAsync(cursorA, 0, (size_t)N_NODES * 4, stream);
    k_hist_rank<<<EBLK, 256, 0, stream>>>(edst, cursorA, rank);
    k_partial<<<N_SBLK, 256, 0, stream>>>(cursorA, partialsA);
    k_scan_small<<<1, 128, 0, stream>>>(partialsA);
    k_scan_apply<<<N_SBLK, 256, 0, stream>>>(cursorA, row_startA, partialsA);
    k_scatter_rank<<<EBLK, 256, 0, stream>>>(esrc, edst, ew, a3,
                                             row_startA, rank, col_w);
    k_bias_csr2<<<NBLK, 256, 0, stream>>>(row_startA, col_w, labels, a2, a4, biasA);

    k_pull2<1><<<PBLK, 256, 0, stream>>>(xa0, row_startA, col_w, biasA, a1, nullptr, xa1);
    k_pull2<1><<<PBLK, 256, 0, stream>>>(xa1, row_startA, col_w, biasA, a1, nullptr, xa0);
    k_pull2<1><<<PBLK, 256, 0, stream>>>(xa0, row_startA, col_w, biasA, a1, nullptr, xa1);
    k_pull2<0><<<PBLK, 256, 0, stream>>>(xa1, row_startA, col_w, biasA, a1, (float4*)out, nullptr);
  } else if (ws_size >= need_B) {
    // ---- tier B: round-8 path (proven) ----
    k_cvt<<<CBLK, 256, 0, stream>>>((const float4*)x0, xb0);
    hipMemsetAsync(cursorB, 0, (size_t)N_NODES * 4, stream);
    k_hist<<<EBLK, 256, 0, stream>>>(edst, cursorB);
    k_partial<<<N_SBLK, 256, 0, stream>>>(cursorB, partialsB);
    k_scan_small<<<1, 128, 0, stream>>>(partialsB);
    k_scan_apply<<<N_SBLK, 256, 0, stream>>>(cursorB, row_startB, partialsB);
    k_sort<<<EBLK, 256, 0, stream>>>(esrc, edst, ew, a3, cursorB, colB, wsorted);
    k_bias_csr<<<NBLK, 256, 0, stream>>>(row_startB, wsorted, labels, a2, a4, biasB);

    k_pull<1><<<PBLK, 256, 0, stream>>>(xb0, row_startB, colB, biasB, a1, nullptr, xb1);
    k_pull<1><<<PBLK, 256, 0, stream>>>(xb1, row_startB, colB, biasB, a1, nullptr, xb0);
    k_pull<1><<<PBLK, 256, 0, stream>>>(xb0, row_startB, colB, biasB, a1, nullptr, xb1);
    k_pull<0><<<PBLK, 256, 0, stream>>>(xb1, row_startB, colB, biasB, a1, (float4*)out, nullptr);
  } else {
    // ---- tier C: atomic push fallback ----
    float* neigh  = (float*)ws;
    float* esums  = (float*)(ws + (size_t)N_NODES * D * 4);
    float* fbias  = esums + N_NODES;
    hipMemsetAsync(esums, 0, N_NODES * 4, stream);
    k_hist_legacy<<<EBLK, 256, 0, stream>>>(ew, edst, a3, esums);
    k_bias_only<<<NBLK, 256, 0, stream>>>(esums, labels, a2, a4, fbias);
    const float* xin = x0;
    for (int it = 0; it < 4; ++it) {
      hipMemsetAsync(neigh, 0, (size_t)N_NODES * D * 4, stream);
      long long tt = (long long)N_EDGES * 64;
      k_scatter<<<(int)(tt / 256), 256, 0, stream>>>(xin, esrc, edst, neigh);
      k_relu<<<CBLK, 256, 0, stream>>>((const float4*)neigh, fbias, a1, (float4*)out);
      xin = out;
    }
  }
}

// Round 10
// 736.503 us; speedup vs baseline: 4.1699x; 1.0016x over previous
//
#include <hip/hip_runtime.h>

constexpr int N_NODES = 100000;
constexpr int N_EDGES = 3200000;
constexpr int D = 64;
constexpr int SCAN_CHUNK = 1024;
constexpr int N_SBLK = (N_NODES + SCAN_CHUNK - 1) / SCAN_CHUNK;  // 98
constexpr int EBLK = (N_EDGES + 255) / 256;                      // 12500
constexpr int CBLK = (N_NODES * (D / 4) + 255) / 256;            // 6250

typedef unsigned short ushort8v __attribute__((ext_vector_type(8)));

// ---------- bf16 helpers (manual RNE; no NaN/Inf in this workload) ----------
__device__ __forceinline__ float bf2f(unsigned short u) {
  union { unsigned int i; float f; } c; c.i = ((unsigned int)u) << 16; return c.f;
}
__device__ __forceinline__ unsigned short f2bf(float f) {
  union { float f; unsigned int i; } c; c.f = f;
  unsigned int b = c.i;
  return (unsigned short)((b + 0x7FFFu + ((b >> 16) & 1u)) >> 16);
}

// ============================ CSR build =================================

// Fused: histogram+rank (blocks 0..EBLK) and f32->bf16 cvt (blocks EBLK..).
__global__ __launch_bounds__(256) void k_hist_rank_cvt(
    const int* __restrict__ dst, int* __restrict__ deg,
    unsigned short* __restrict__ rank,
    const float4* __restrict__ xin, ushort4* __restrict__ xout) {
  int b = blockIdx.x;
  if (b < EBLK) {
    int e = b * 256 + threadIdx.x;
    if (e < N_EDGES) rank[e] = (unsigned short)atomicAdd(&deg[dst[e]], 1);
  } else {
    int t = (b - EBLK) * 256 + threadIdx.x;
    if (t < N_NODES * (D / 4)) {
      float4 v = xin[t];
      ushort4 r;
      r.x = f2bf(v.x); r.y = f2bf(v.y); r.z = f2bf(v.z); r.w = f2bf(v.w);
      xout[t] = r;
    }
  }
}

// Legacy histogram (tier-B path).
__global__ __launch_bounds__(256) void k_hist(
    const int* __restrict__ dst, int* __restrict__ deg_cursor) {
  int e = blockIdx.x * 256 + threadIdx.x;
  if (e >= N_EDGES) return;
  atomicAdd(&deg_cursor[dst[e]], 1);
}

// Two-level scan, stage 1: per-1024-node-chunk degree sums.
__global__ __launch_bounds__(256) void k_partial(
    const int* __restrict__ deg, int* __restrict__ partials) {
  __shared__ int red[256];
  int t = threadIdx.x;
  int base = blockIdx.x * SCAN_CHUNK + t * 4;
  int s = 0;
#pragma unroll
  for (int k = 0; k < 4; ++k) {
    int i = base + k;
    if (i < N_NODES) s += deg[i];
  }
  red[t] = s;
  __syncthreads();
  for (int off = 128; off > 0; off >>= 1) {
    if (t < off) red[t] += red[t + off];
    __syncthreads();
  }
  if (t == 0) partials[blockIdx.x] = red[0];
}

// Stage 2: exclusive scan of the 98 partials.
__global__ __launch_bounds__(128) void k_scan_small(int* __restrict__ partials) {
  __shared__ int sh[128];
  int t = threadIdx.x;
  int v = (t < N_SBLK) ? partials[t] : 0;
  sh[t] = v;
  __syncthreads();
  for (int off = 1; off < 128; off <<= 1) {
    int u = (t >= off) ? sh[t - off] : 0;
    __syncthreads();
    sh[t] += u;
    __syncthreads();
  }
  if (t < N_SBLK) partials[t] = sh[t] - v;  // exclusive
}

// Stage 3: block-local scan + apply. Emits row_start (and cursor copy).
__global__ __launch_bounds__(256) void k_scan_apply(
    int* __restrict__ deg_cursor,        // in: deg, out: cursor (=row_start)
    int* __restrict__ row_start,         // out: [N+1]
    const int* __restrict__ partials) {
  __shared__ int sh[256];
  int b = blockIdx.x, t = threadIdx.x;
  int base = b * SCAN_CHUNK + t * 4;
  int d[4];
  int s = 0;
#pragma unroll
  for (int k = 0; k < 4; ++k) {
    int i = base + k;
    d[k] = (i < N_NODES) ? deg_cursor[i] : 0;
    s += d[k];
  }
  sh[t] = s;
  __syncthreads();
  for (int off = 1; off < 256; off <<= 1) {  // Hillis-Steele inclusive
    int u = (t >= off) ? sh[t - off] : 0;
    __syncthreads();
    sh[t] += u;
    __syncthreads();
  }
  int run = partials[b] + sh[t] - s;  // exclusive prefix for this thread
#pragma unroll
  for (int k = 0; k < 4; ++k) {
    int i = base + k;
    if (i < N_NODES) {
      row_start[i] = run;
      deg_cursor[i] = run;
      run += d[k];
    }
  }
  if (b == 0 && t == 0) row_start[N_NODES] = N_EDGES;
}

// Non-atomic scatter: pos = row_start[dst] + rank; 4B col + 4B wsorted.
__global__ __launch_bounds__(256) void k_scatter_rank2(
    const int* __restrict__ src, const int* __restrict__ dst,
    const float* __restrict__ ew, const float* __restrict__ a3,
    const int* __restrict__ row_start, const unsigned short* __restrict__ rank,
    int* __restrict__ col, float* __restrict__ wsorted) {
  int e = blockIdx.x * 256 + threadIdx.x;
  if (e >= N_EDGES) return;
  int pos = row_start[dst[e]] + (int)rank[e];
  col[pos] = src[e];
  wsorted[pos] = fmaxf(a3[0] * ew[e], 0.0f);
}

// bias[n] = a2 * sum(wsorted[row]) + a4 * labels[n]
__global__ __launch_bounds__(256) void k_bias_csr(
    const int* __restrict__ row_start, const float* __restrict__ wsorted,
    const int* __restrict__ labels,
    const float* __restrict__ a2, const float* __restrict__ a4,
    float* __restrict__ bias) {
  int n = blockIdx.x * 256 + threadIdx.x;
  if (n >= N_NODES) return;
  int beg = row_start[n], end = row_start[n + 1];
  float s = 0.f;
  for (int j = beg; j < end; ++j) s += wsorted[j];
  bias[n] = a2[0] * s + a4[0] * (float)labels[n];
}

// f32 -> bf16 conversion (tier-B).
__global__ __launch_bounds__(256) void k_cvt(
    const float4* __restrict__ xin, ushort4* __restrict__ xout) {
  int t = blockIdx.x * 256 + threadIdx.x;
  if (t >= N_NODES * (D / 4)) return;
  float4 v = xin[t];
  ushort4 r;
  r.x = f2bf(v.x); r.y = f2bf(v.y); r.z = f2bf(v.z); r.w = f2bf(v.w);
  xout[t] = r;
}

// ====================== pull iteration (no atomics) =====================
// One wave per node; 8 edge slots x 8 lanes x 16B (ushort8 = dwordx4).
// Software-pipelined col prefetch to break the col->gather latency chain.
template <int WRITE_BF16>
__global__ __launch_bounds__(256) void k_pull3(
    const ushort8v* __restrict__ x,
    const int* __restrict__ row_start,
    const int* __restrict__ col,
    const float* __restrict__ bias,
    const float* __restrict__ a1,
    float4* __restrict__ outf, ushort8v* __restrict__ outb) {
  int node = (blockIdx.x * 256 + threadIdx.x) >> 6;
  if (node >= N_NODES) return;
  int lane = threadIdx.x & 63;
  int slot = lane >> 3;   // 0..7: edge slot
  int l8 = lane & 7;      // 16B chunk of the 128B row
  int beg = row_start[node], end = row_start[node + 1];
  float acc[8] = {0.f, 0.f, 0.f, 0.f, 0.f, 0.f, 0.f, 0.f};

  int j = beg + slot;
  int s0 = (j < end) ? col[j] : -1;
  int s1 = (j + 8 < end) ? col[j + 8] : -1;
  while (s0 >= 0) {
    int j2 = j + 16;
    int n0 = (j2 < end) ? col[j2] : -1;
    int n1 = (j2 + 8 < end) ? col[j2 + 8] : -1;
    ushort8v v0 = x[s0 * 8 + l8];
#pragma unroll
    for (int k = 0; k < 8; ++k) acc[k] += bf2f(v0[k]);
    if (s1 >= 0) {
      ushort8v v1 = x[s1 * 8 + l8];
#pragma unroll
      for (int k = 0; k < 8; ++k) acc[k] += bf2f(v1[k]);
    }
    s0 = n0; s1 = n1; j = j2;
  }
#pragma unroll
  for (int k = 0; k < 8; ++k) {
    acc[k] += __shfl_xor(acc[k], 8);
    acc[k] += __shfl_xor(acc[k], 16);
    acc[k] += __shfl_xor(acc[k], 32);
  }
  if (slot == 0) {
    float al = a1[0], b = bias[node];
#pragma unroll
    for (int k = 0; k < 8; ++k) acc[k] = fmaxf(fmaf(al, acc[k], b), 0.f);
    if (WRITE_BF16) {
      ushort8v r;
#pragma unroll
      for (int k = 0; k < 8; ++k) r[k] = f2bf(acc[k]);
      outb[node * 8 + l8] = r;
    } else {
      float4 r0, r1;
      r0.x = acc[0]; r0.y = acc[1]; r0.z = acc[2]; r0.w = acc[3];
      r1.x = acc[4]; r1.y = acc[5]; r1.z = acc[6]; r1.w = acc[7];
      outf[node * 16 + l8 * 2] = r0;
      outf[node * 16 + l8 * 2 + 1] = r1;
    }
  }
}

// =================== tier-B kernels (round-8 CSR path) ==================

__global__ __launch_bounds__(256) void k_sort(
    const int* __restrict__ src, const int* __restrict__ dst,
    const float* __restrict__ ew, const float* __restrict__ a3,
    int* __restrict__ cursor, int* __restrict__ col,
    float* __restrict__ wsorted) {
  int e = blockIdx.x * 256 + threadIdx.x;
  if (e >= N_EDGES) return;
  int pos = atomicAdd(&cursor[dst[e]], 1);
  col[pos] = src[e];
  wsorted[pos] = fmaxf(a3[0] * ew[e], 0.0f);
}

template <int WRITE_BF16>
__global__ __launch_bounds__(256) void k_pull(
    const ushort4* __restrict__ x,
    const int* __restrict__ row_start,
    const int* __restrict__ col,
    const float* __restrict__ bias,
    const float* __restrict__ a1,
    float4* __restrict__ outf, ushort4* __restrict__ outb) {
  int node = (blockIdx.x * 256 + threadIdx.x) >> 6;
  if (node >= N_NODES) return;
  int lane = threadIdx.x & 63;
  int sub = lane >> 4;
  int l16 = lane & 15;
  int beg = row_start[node], end = row_start[node + 1];
  float ax = 0.f, ay = 0.f, az = 0.f, aw = 0.f;
  for (int j = beg + sub; j < end; j += 4) {
    int s = col[j];
    ushort4 v = x[s * 16 + l16];
    ax += bf2f(v.x); ay += bf2f(v.y); az += bf2f(v.z); aw += bf2f(v.w);
  }
  ax += __shfl_xor(ax, 16); ay += __shfl_xor(ay, 16);
  az += __shfl_xor(az, 16); aw += __shfl_xor(aw, 16);
  ax += __shfl_xor(ax, 32); ay += __shfl_xor(ay, 32);
  az += __shfl_xor(az, 32); aw += __shfl_xor(aw, 32);
  if (sub == 0) {
    float al = a1[0], b = bias[node];
    float rx = fmaxf(fmaf(al, ax, b), 0.f);
    float ry = fmaxf(fmaf(al, ay, b), 0.f);
    float rz = fmaxf(fmaf(al, az, b), 0.f);
    float rw = fmaxf(fmaf(al, aw, b), 0.f);
    if (WRITE_BF16) {
      ushort4 r;
      r.x = f2bf(rx); r.y = f2bf(ry); r.z = f2bf(rz); r.w = f2bf(rw);
      outb[node * 16 + l16] = r;
    } else {
      float4 r; r.x = rx; r.y = ry; r.z = rz; r.w = rw;
      outf[node * 16 + l16] = r;
    }
  }
}

// ===================== fallback (atomic push path) ======================

__global__ __launch_bounds__(256) void k_hist_legacy(
    const float* __restrict__ ew, const int* __restrict__ dst,
    const float* __restrict__ a3, float* __restrict__ edge_sums) {
  int e = blockIdx.x * 256 + threadIdx.x;
  if (e >= N_EDGES) return;
  atomicAdd(&edge_sums[dst[e]], fmaxf(a3[0] * ew[e], 0.0f));
}

__global__ __launch_bounds__(256) void k_bias_only(
    const float* __restrict__ edge_sums, const int* __restrict__ labels,
    const float* __restrict__ a2, const float* __restrict__ a4,
    float* __restrict__ bias) {
  int n = blockIdx.x * 256 + threadIdx.x;
  if (n >= N_NODES) return;
  bias[n] = a2[0] * edge_sums[n] + a4[0] * (float)labels[n];
}

__global__ __launch_bounds__(256) void k_scatter(
    const float* __restrict__ x, const int* __restrict__ src,
    const int* __restrict__ dst, float* __restrict__ neigh) {
  long long t = (long long)blockIdx.x * 256 + threadIdx.x;
  int e = (int)(t >> 6);
  int lane = (int)(t & 63);
  if (e >= N_EDGES) return;
  atomicAdd(&neigh[dst[e] * D + lane], x[src[e] * D + lane]);
}

__global__ __launch_bounds__(256) void k_relu(
    const float4* __restrict__ neigh, const float* __restrict__ bias,
    const float* __restrict__ a1, float4* __restrict__ xout) {
  int t = blockIdx.x * 256 + threadIdx.x;
  if (t >= N_NODES * (D / 4)) return;
  int n = t >> 4;
  float al = a1[0], b = bias[n];
  float4 v = neigh[t];
  float4 r;
  r.x = fmaxf(al * v.x + b, 0.f);
  r.y = fmaxf(al * v.y + b, 0.f);
  r.z = fmaxf(al * v.z + b, 0.f);
  r.w = fmaxf(al * v.w + b, 0.f);
  xout[t] = r;
}

// ============================== launch ==================================

extern "C" void kernel_launch(void* const* d_in, const int* in_sizes, int n_in,
                              void* d_out, int out_size, void* d_ws, size_t ws_size,
                              hipStream_t stream) {
  const float* x0     = (const float*)d_in[0];
  const float* ew     = (const float*)d_in[1];
  const float* a1     = (const float*)d_in[2];
  const float* a2     = (const float*)d_in[3];
  const float* a3     = (const float*)d_in[4];
  const float* a4     = (const float*)d_in[5];
  const int*   esrc   = (const int*)d_in[6];
  const int*   edst   = (const int*)d_in[7];
  const int*   labels = (const int*)d_in[8];
  float* out = (float*)d_out;

  char* ws = (char*)d_ws;
  const int PBLK = (N_NODES * 64 + 255) / 256;
  const int NBLK = (N_NODES + 255) / 256;

  // ---------------- tier A layout (~46.6 MB) ----------------
  size_t offA = 0;
  int*   cursorA    = (int*)(ws + offA);   offA += (size_t)N_NODES * 4;        // 400000
  int*   row_startA = (int*)(ws + offA);   offA += (size_t)(N_NODES + 4) * 4;  // 400016
  float* biasA      = (float*)(ws + offA); offA += (size_t)N_NODES * 4;
  int*   partialsA  = (int*)(ws + offA);   offA += 128 * 4;
  int*   colA       = (int*)(ws + offA);   offA += (size_t)N_EDGES * 4;        // 12.8M
  unsigned short* rank = (unsigned short*)(ws + offA); offA += (size_t)N_EDGES * 2; // 6.4M
  ushort4* xa0      = (ushort4*)(ws + offA); offA += (size_t)N_NODES * D * 2;  // 12.8M
  // wsorted (E*4 = 12.8MB) aliases xa1: wsorted dead after k_bias_csr,
  // xa1 first written by pull #1 (stream-ordered).
  char* aliasA      = ws + offA;           offA += (size_t)N_EDGES * 4;
  float*   wsortedA = (float*)aliasA;
  ushort4* xa1      = (ushort4*)aliasA;
  const size_t need_A = offA;

  // ---------------- tier B layout (~39.8 MB, round-8) ----------------
  size_t offB = 0;
  int*   cursorB    = (int*)(ws + offB);   offB += (size_t)N_NODES * 4;
  int*   row_startB = (int*)(ws + offB);   offB += (size_t)(N_NODES + 4) * 4;
  float* biasB      = (float*)(ws + offB); offB += (size_t)N_NODES * 4;
  int*   partialsB  = (int*)(ws + offB);   offB += 128 * 4;
  int*   colB       = (int*)(ws + offB);   offB += (size_t)N_EDGES * 4;
  ushort4* xb0      = (ushort4*)(ws + offB); offB += (size_t)N_NODES * D * 2;
  char* aliasB      = ws + offB;           offB += (size_t)N_EDGES * 4;
  float*   wsortedB = (float*)aliasB;
  ushort4* xb1      = (ushort4*)aliasB;
  const size_t need_B = offB;

  if (ws_size >= need_A) {
    // ---- tier A: rank CSR + 8-lane pipelined pulls ----
    hipMemsetAsync(cursorA, 0, (size_t)N_NODES * 4, stream);
    k_hist_rank_cvt<<<EBLK + CBLK, 256, 0, stream>>>(
        edst, cursorA, rank, (const float4*)x0, xa0);
    k_partial<<<N_SBLK, 256, 0, stream>>>(cursorA, partialsA);
    k_scan_small<<<1, 128, 0, stream>>>(partialsA);
    k_scan_apply<<<N_SBLK, 256, 0, stream>>>(cursorA, row_startA, partialsA);
    k_scatter_rank2<<<EBLK, 256, 0, stream>>>(esrc, edst, ew, a3,
                                              row_startA, rank, colA, wsortedA);
    k_bias_csr<<<NBLK, 256, 0, stream>>>(row_startA, wsortedA, labels, a2, a4, biasA);

    k_pull3<1><<<PBLK, 256, 0, stream>>>((const ushort8v*)xa0, row_startA, colA,
                                         biasA, a1, nullptr, (ushort8v*)xa1);
    k_pull3<1><<<PBLK, 256, 0, stream>>>((const ushort8v*)xa1, row_startA, colA,
                                         biasA, a1, nullptr, (ushort8v*)xa0);
    k_pull3<1><<<PBLK, 256, 0, stream>>>((const ushort8v*)xa0, row_startA, colA,
                                         biasA, a1, nullptr, (ushort8v*)xa1);
    k_pull3<0><<<PBLK, 256, 0, stream>>>((const ushort8v*)xa1, row_startA, colA,
                                         biasA, a1, (float4*)out, nullptr);
  } else if (ws_size >= need_B) {
    // ---- tier B: round-8 path (proven) ----
    k_cvt<<<CBLK, 256, 0, stream>>>((const float4*)x0, xb0);
    hipMemsetAsync(cursorB, 0, (size_t)N_NODES * 4, stream);
    k_hist<<<EBLK, 256, 0, stream>>>(edst, cursorB);
    k_partial<<<N_SBLK, 256, 0, stream>>>(cursorB, partialsB);
    k_scan_small<<<1, 128, 0, stream>>>(partialsB);
    k_scan_apply<<<N_SBLK, 256, 0, stream>>>(cursorB, row_startB, partialsB);
    k_sort<<<EBLK, 256, 0, stream>>>(esrc, edst, ew, a3, cursorB, colB, wsortedB);
    k_bias_csr<<<NBLK, 256, 0, stream>>>(row_startB, wsortedB, labels, a2, a4, biasB);

    k_pull<1><<<PBLK, 256, 0, stream>>>(xb0, row_startB, colB, biasB, a1, nullptr, xb1);
    k_pull<1><<<PBLK, 256, 0, stream>>>(xb1, row_startB, colB, biasB, a1, nullptr, xb0);
    k_pull<1><<<PBLK, 256, 0, stream>>>(xb0, row_startB, colB, biasB, a1, nullptr, xb1);
    k_pull<0><<<PBLK, 256, 0, stream>>>(xb1, row_startB, colB, biasB, a1, (float4*)out, nullptr);
  } else {
    // ---- tier C: atomic push fallback ----
    float* neigh  = (float*)ws;
    float* esums  = (float*)(ws + (size_t)N_NODES * D * 4);
    float* fbias  = esums + N_NODES;
    hipMemsetAsync(esums, 0, N_NODES * 4, stream);
    k_hist_legacy<<<EBLK, 256, 0, stream>>>(ew, edst, a3, esums);
    k_bias_only<<<NBLK, 256, 0, stream>>>(esums, labels, a2, a4, fbias);
    const float* xin = x0;
    for (int it = 0; it < 4; ++it) {
      hipMemsetAsync(neigh, 0, (size_t)N_NODES * D * 4, stream);
      long long tt = (long long)N_EDGES * 64;
      k_scatter<<<(int)(tt / 256), 256, 0, stream>>>(xin, esrc, edst, neigh);
      k_relu<<<CBLK, 256, 0, stream>>>((const float4*)neigh, fbias, a1, (float4*)out);
      xin = out;
    }
  }
}

// Round 11
// 675.085 us; speedup vs baseline: 4.5493x; 1.0910x over previous
//
#include <hip/hip_runtime.h>

constexpr int N_NODES = 100000;
constexpr int N_EDGES = 3200000;
constexpr int D = 64;
constexpr int SCAN_CHUNK = 1024;
constexpr int N_SBLK = (N_NODES + SCAN_CHUNK - 1) / SCAN_CHUNK;  // 98
constexpr int EBLK = (N_EDGES + 255) / 256;                      // 12500
constexpr int CBLK = (N_NODES * (D / 4) + 255) / 256;            // 6250

typedef unsigned short ushort8v __attribute__((ext_vector_type(8)));

// ---------- bf16 helpers (manual RNE; no NaN/Inf in this workload) ----------
__device__ __forceinline__ float bf2f(unsigned short u) {
  union { unsigned int i; float f; } c; c.i = ((unsigned int)u) << 16; return c.f;
}
__device__ __forceinline__ unsigned short f2bf(float f) {
  union { float f; unsigned int i; } c; c.f = f;
  unsigned int b = c.i;
  return (unsigned short)((b + 0x7FFFu + ((b >> 16) & 1u)) >> 16);
}

// ============================ CSR build =================================

// Fused: histogram+rank (blocks 0..EBLK) and f32->bf16 cvt (blocks EBLK..).
__global__ __launch_bounds__(256) void k_hist_rank_cvt(
    const int* __restrict__ dst, int* __restrict__ deg,
    unsigned short* __restrict__ rank,
    const float4* __restrict__ xin, ushort4* __restrict__ xout) {
  int b = blockIdx.x;
  if (b < EBLK) {
    int e = b * 256 + threadIdx.x;
    if (e < N_EDGES) rank[e] = (unsigned short)atomicAdd(&deg[dst[e]], 1);
  } else {
    int t = (b - EBLK) * 256 + threadIdx.x;
    if (t < N_NODES * (D / 4)) {
      float4 v = xin[t];
      ushort4 r;
      r.x = f2bf(v.x); r.y = f2bf(v.y); r.z = f2bf(v.z); r.w = f2bf(v.w);
      xout[t] = r;
    }
  }
}

// Legacy histogram (tier-B path).
__global__ __launch_bounds__(256) void k_hist(
    const int* __restrict__ dst, int* __restrict__ deg_cursor) {
  int e = blockIdx.x * 256 + threadIdx.x;
  if (e >= N_EDGES) return;
  atomicAdd(&deg_cursor[dst[e]], 1);
}

// Two-level scan, stage 1: per-1024-node-chunk degree sums.
__global__ __launch_bounds__(256) void k_partial(
    const int* __restrict__ deg, int* __restrict__ partials) {
  __shared__ int red[256];
  int t = threadIdx.x;
  int base = blockIdx.x * SCAN_CHUNK + t * 4;
  int s = 0;
#pragma unroll
  for (int k = 0; k < 4; ++k) {
    int i = base + k;
    if (i < N_NODES) s += deg[i];
  }
  red[t] = s;
  __syncthreads();
  for (int off = 128; off > 0; off >>= 1) {
    if (t < off) red[t] += red[t + off];
    __syncthreads();
  }
  if (t == 0) partials[blockIdx.x] = red[0];
}

// Stage 2: exclusive scan of the 98 partials.
__global__ __launch_bounds__(128) void k_scan_small(int* __restrict__ partials) {
  __shared__ int sh[128];
  int t = threadIdx.x;
  int v = (t < N_SBLK) ? partials[t] : 0;
  sh[t] = v;
  __syncthreads();
  for (int off = 1; off < 128; off <<= 1) {
    int u = (t >= off) ? sh[t - off] : 0;
    __syncthreads();
    sh[t] += u;
    __syncthreads();
  }
  if (t < N_SBLK) partials[t] = sh[t] - v;  // exclusive
}

// Stage 3: block-local scan + apply. Emits row_start (and cursor copy).
__global__ __launch_bounds__(256) void k_scan_apply(
    int* __restrict__ deg_cursor,        // in: deg, out: cursor (=row_start)
    int* __restrict__ row_start,         // out: [N+1]
    const int* __restrict__ partials) {
  __shared__ int sh[256];
  int b = blockIdx.x, t = threadIdx.x;
  int base = b * SCAN_CHUNK + t * 4;
  int d[4];
  int s = 0;
#pragma unroll
  for (int k = 0; k < 4; ++k) {
    int i = base + k;
    d[k] = (i < N_NODES) ? deg_cursor[i] : 0;
    s += d[k];
  }
  sh[t] = s;
  __syncthreads();
  for (int off = 1; off < 256; off <<= 1) {  // Hillis-Steele inclusive
    int u = (t >= off) ? sh[t - off] : 0;
    __syncthreads();
    sh[t] += u;
    __syncthreads();
  }
  int run = partials[b] + sh[t] - s;  // exclusive prefix for this thread
#pragma unroll
  for (int k = 0; k < 4; ++k) {
    int i = base + k;
    if (i < N_NODES) {
      row_start[i] = run;
      deg_cursor[i] = run;
      run += d[k];
    }
  }
  if (b == 0 && t == 0) row_start[N_NODES] = N_EDGES;
}

// Non-atomic scatter: pos = row_start[dst] + rank; single fused 8B store.
__global__ __launch_bounds__(256) void k_scatter_rank(
    const int* __restrict__ src, const int* __restrict__ dst,
    const float* __restrict__ ew, const float* __restrict__ a3,
    const int* __restrict__ row_start, const unsigned short* __restrict__ rank,
    int2* __restrict__ col_w) {
  int e = blockIdx.x * 256 + threadIdx.x;
  if (e >= N_EDGES) return;
  int pos = row_start[dst[e]] + (int)rank[e];
  int2 v;
  v.x = src[e];
  v.y = __float_as_int(fmaxf(a3[0] * ew[e], 0.0f));
  col_w[pos] = v;
}

// ====================== pull iteration (no atomics) =====================
// One wave per node; 8 edge slots x 8 lanes x 16B (ushort8 = dwordx4).
// 4-deep unconditional row loads (mask-multiply guards) for MLP.
// FIRST: also computes bias = a2*sum(w) + a4*label inline and stores it.
template <int FIRST, int WRITE_BF16>
__global__ __launch_bounds__(256) void k_pull4(
    const ushort8v* __restrict__ x,
    const int* __restrict__ row_start,
    const int2* __restrict__ col_w,
    float* __restrict__ bias,
    const int* __restrict__ labels,
    const float* __restrict__ a1, const float* __restrict__ a2,
    const float* __restrict__ a4,
    float4* __restrict__ outf, ushort8v* __restrict__ outb) {
  int node = (blockIdx.x * 256 + threadIdx.x) >> 6;
  if (node >= N_NODES) return;
  int lane = threadIdx.x & 63;
  int slot = lane >> 3;   // 0..7: edge slot
  int l8 = lane & 7;      // 16B chunk of the 128B row
  int beg = row_start[node], end = row_start[node + 1];
  float acc[8] = {0.f, 0.f, 0.f, 0.f, 0.f, 0.f, 0.f, 0.f};
  float accw = 0.f;
  int jm = end - 1;
  for (int j = beg + slot; j < end; j += 32) {
    int j1 = j + 8, j2 = j + 16, j3 = j + 24;
    float m1 = (j1 < end) ? 1.f : 0.f;
    float m2 = (j2 < end) ? 1.f : 0.f;
    float m3 = (j3 < end) ? 1.f : 0.f;
    j1 = (j1 < end) ? j1 : jm;
    j2 = (j2 < end) ? j2 : jm;
    j3 = (j3 < end) ? j3 : jm;
    int2 c0 = col_w[j];
    int2 c1 = col_w[j1];
    int2 c2 = col_w[j2];
    int2 c3 = col_w[j3];
    ushort8v v0 = x[c0.x * 8 + l8];
    ushort8v v1 = x[c1.x * 8 + l8];
    ushort8v v2 = x[c2.x * 8 + l8];
    ushort8v v3 = x[c3.x * 8 + l8];
#pragma unroll
    for (int k = 0; k < 8; ++k) {
      acc[k] += bf2f(v0[k]);
      acc[k] = fmaf(m1, bf2f(v1[k]), acc[k]);
      acc[k] = fmaf(m2, bf2f(v2[k]), acc[k]);
      acc[k] = fmaf(m3, bf2f(v3[k]), acc[k]);
    }
    if (FIRST) {
      accw += __int_as_float(c0.y);
      accw = fmaf(m1, __int_as_float(c1.y), accw);
      accw = fmaf(m2, __int_as_float(c2.y), accw);
      accw = fmaf(m3, __int_as_float(c3.y), accw);
    }
  }
#pragma unroll
  for (int k = 0; k < 8; ++k) {
    acc[k] += __shfl_xor(acc[k], 8);
    acc[k] += __shfl_xor(acc[k], 16);
    acc[k] += __shfl_xor(acc[k], 32);
  }
  float b;
  if (FIRST) {
    accw += __shfl_xor(accw, 8);
    accw += __shfl_xor(accw, 16);
    accw += __shfl_xor(accw, 32);
    b = a2[0] * accw + a4[0] * (float)labels[node];
    if (lane == 0) bias[node] = b;
  } else {
    b = bias[node];
  }
  if (slot == 0) {
    float al = a1[0];
#pragma unroll
    for (int k = 0; k < 8; ++k) acc[k] = fmaxf(fmaf(al, acc[k], b), 0.f);
    if (WRITE_BF16) {
      ushort8v r;
#pragma unroll
      for (int k = 0; k < 8; ++k) r[k] = f2bf(acc[k]);
      outb[node * 8 + l8] = r;
    } else {
      float4 r0, r1;
      r0.x = acc[0]; r0.y = acc[1]; r0.z = acc[2]; r0.w = acc[3];
      r1.x = acc[4]; r1.y = acc[5]; r1.z = acc[6]; r1.w = acc[7];
      outf[node * 16 + l8 * 2] = r0;
      outf[node * 16 + l8 * 2 + 1] = r1;
    }
  }
}

// =================== tier-B kernels (round-8 CSR path) ==================

__global__ __launch_bounds__(256) void k_cvt(
    const float4* __restrict__ xin, ushort4* __restrict__ xout) {
  int t = blockIdx.x * 256 + threadIdx.x;
  if (t >= N_NODES * (D / 4)) return;
  float4 v = xin[t];
  ushort4 r;
  r.x = f2bf(v.x); r.y = f2bf(v.y); r.z = f2bf(v.z); r.w = f2bf(v.w);
  xout[t] = r;
}

__global__ __launch_bounds__(256) void k_sort(
    const int* __restrict__ src, const int* __restrict__ dst,
    const float* __restrict__ ew, const float* __restrict__ a3,
    int* __restrict__ cursor, int* __restrict__ col,
    float* __restrict__ wsorted) {
  int e = blockIdx.x * 256 + threadIdx.x;
  if (e >= N_EDGES) return;
  int pos = atomicAdd(&cursor[dst[e]], 1);
  col[pos] = src[e];
  wsorted[pos] = fmaxf(a3[0] * ew[e], 0.0f);
}

__global__ __launch_bounds__(256) void k_bias_csr(
    const int* __restrict__ row_start, const float* __restrict__ wsorted,
    const int* __restrict__ labels,
    const float* __restrict__ a2, const float* __restrict__ a4,
    float* __restrict__ bias) {
  int n = blockIdx.x * 256 + threadIdx.x;
  if (n >= N_NODES) return;
  int beg = row_start[n], end = row_start[n + 1];
  float s = 0.f;
  for (int j = beg; j < end; ++j) s += wsorted[j];
  bias[n] = a2[0] * s + a4[0] * (float)labels[n];
}

template <int WRITE_BF16>
__global__ __launch_bounds__(256) void k_pull(
    const ushort4* __restrict__ x,
    const int* __restrict__ row_start,
    const int* __restrict__ col,
    const float* __restrict__ bias,
    const float* __restrict__ a1,
    float4* __restrict__ outf, ushort4* __restrict__ outb) {
  int node = (blockIdx.x * 256 + threadIdx.x) >> 6;
  if (node >= N_NODES) return;
  int lane = threadIdx.x & 63;
  int sub = lane >> 4;
  int l16 = lane & 15;
  int beg = row_start[node], end = row_start[node + 1];
  float ax = 0.f, ay = 0.f, az = 0.f, aw = 0.f;
  for (int j = beg + sub; j < end; j += 4) {
    int s = col[j];
    ushort4 v = x[s * 16 + l16];
    ax += bf2f(v.x); ay += bf2f(v.y); az += bf2f(v.z); aw += bf2f(v.w);
  }
  ax += __shfl_xor(ax, 16); ay += __shfl_xor(ay, 16);
  az += __shfl_xor(az, 16); aw += __shfl_xor(aw, 16);
  ax += __shfl_xor(ax, 32); ay += __shfl_xor(ay, 32);
  az += __shfl_xor(az, 32); aw += __shfl_xor(aw, 32);
  if (sub == 0) {
    float al = a1[0], b = bias[node];
    float rx = fmaxf(fmaf(al, ax, b), 0.f);
    float ry = fmaxf(fmaf(al, ay, b), 0.f);
    float rz = fmaxf(fmaf(al, az, b), 0.f);
    float rw = fmaxf(fmaf(al, aw, b), 0.f);
    if (WRITE_BF16) {
      ushort4 r;
      r.x = f2bf(rx); r.y = f2bf(ry); r.z = f2bf(rz); r.w = f2bf(rw);
      outb[node * 16 + l16] = r;
    } else {
      float4 r; r.x = rx; r.y = ry; r.z = rz; r.w = rw;
      outf[node * 16 + l16] = r;
    }
  }
}

// ===================== fallback (atomic push path) ======================

__global__ __launch_bounds__(256) void k_hist_legacy(
    const float* __restrict__ ew, const int* __restrict__ dst,
    const float* __restrict__ a3, float* __restrict__ edge_sums) {
  int e = blockIdx.x * 256 + threadIdx.x;
  if (e >= N_EDGES) return;
  atomicAdd(&edge_sums[dst[e]], fmaxf(a3[0] * ew[e], 0.0f));
}

__global__ __launch_bounds__(256) void k_bias_only(
    const float* __restrict__ edge_sums, const int* __restrict__ labels,
    const float* __restrict__ a2, const float* __restrict__ a4,
    float* __restrict__ bias) {
  int n = blockIdx.x * 256 + threadIdx.x;
  if (n >= N_NODES) return;
  bias[n] = a2[0] * edge_sums[n] + a4[0] * (float)labels[n];
}

__global__ __launch_bounds__(256) void k_scatter(
    const float* __restrict__ x, const int* __restrict__ src,
    const int* __restrict__ dst, float* __restrict__ neigh) {
  long long t = (long long)blockIdx.x * 256 + threadIdx.x;
  int e = (int)(t >> 6);
  int lane = (int)(t & 63);
  if (e >= N_EDGES) return;
  atomicAdd(&neigh[dst[e] * D + lane], x[src[e] * D + lane]);
}

__global__ __launch_bounds__(256) void k_relu(
    const float4* __restrict__ neigh, const float* __restrict__ bias,
    const float* __restrict__ a1, float4* __restrict__ xout) {
  int t = blockIdx.x * 256 + threadIdx.x;
  if (t >= N_NODES * (D / 4)) return;
  int n = t >> 4;
  float al = a1[0], b = bias[n];
  float4 v = neigh[t];
  float4 r;
  r.x = fmaxf(al * v.x + b, 0.f);
  r.y = fmaxf(al * v.y + b, 0.f);
  r.z = fmaxf(al * v.z + b, 0.f);
  r.w = fmaxf(al * v.w + b, 0.f);
  xout[t] = r;
}

// ============================== launch ==================================

extern "C" void kernel_launch(void* const* d_in, const int* in_sizes, int n_in,
                              void* d_out, int out_size, void* d_ws, size_t ws_size,
                              hipStream_t stream) {
  const float* x0     = (const float*)d_in[0];
  const float* ew     = (const float*)d_in[1];
  const float* a1     = (const float*)d_in[2];
  const float* a2     = (const float*)d_in[3];
  const float* a3     = (const float*)d_in[4];
  const float* a4     = (const float*)d_in[5];
  const int*   esrc   = (const int*)d_in[6];
  const int*   edst   = (const int*)d_in[7];
  const int*   labels = (const int*)d_in[8];
  float* out = (float*)d_out;

  char* ws = (char*)d_ws;
  const int PBLK = (N_NODES * 64 + 255) / 256;
  const int NBLK = (N_NODES + 255) / 256;

  // ---------------- tier A layout (~52.8 MB) ----------------
  size_t offA = 0;
  int*   cursorA    = (int*)(ws + offA);   offA += (size_t)N_NODES * 4;
  int*   row_startA = (int*)(ws + offA);   offA += (size_t)(N_NODES + 4) * 4;
  float* biasA      = (float*)(ws + offA); offA += (size_t)N_NODES * 4;
  int*   partialsA  = (int*)(ws + offA);   offA += 128 * 4;
  int2*  col_w      = (int2*)(ws + offA);  offA += (size_t)N_EDGES * 8;     // 25.6M
  ushort4* xa0      = (ushort4*)(ws + offA); offA += (size_t)N_NODES * D * 2; // 12.8M
  // rank (ushort E = 6.4MB) aliases xa1 (12.8MB): rank dead after
  // k_scatter_rank; xa1 first written by pull #1 (stream-ordered).
  char* aliasA      = ws + offA;           offA += (size_t)N_NODES * D * 2;
  unsigned short* rank = (unsigned short*)aliasA;
  ushort4* xa1      = (ushort4*)aliasA;
  const size_t need_A = offA;

  // ---------------- tier B layout (~39.8 MB, round-8) ----------------
  size_t offB = 0;
  int*   cursorB    = (int*)(ws + offB);   offB += (size_t)N_NODES * 4;
  int*   row_startB = (int*)(ws + offB);   offB += (size_t)(N_NODES + 4) * 4;
  float* biasB      = (float*)(ws + offB); offB += (size_t)N_NODES * 4;
  int*   partialsB  = (int*)(ws + offB);   offB += 128 * 4;
  int*   colB       = (int*)(ws + offB);   offB += (size_t)N_EDGES * 4;
  ushort4* xb0      = (ushort4*)(ws + offB); offB += (size_t)N_NODES * D * 2;
  char* aliasB      = ws + offB;           offB += (size_t)N_EDGES * 4;
  float*   wsortedB = (float*)aliasB;
  ushort4* xb1      = (ushort4*)aliasB;
  const size_t need_B = offB;

  if (ws_size >= need_A) {
    // ---- tier A: rank CSR (int2 fused payload) + bias-fused 4-deep pulls
    hipMemsetAsync(cursorA, 0, (size_t)N_NODES * 4, stream);
    k_hist_rank_cvt<<<EBLK + CBLK, 256, 0, stream>>>(
        edst, cursorA, rank, (const float4*)x0, xa0);
    k_partial<<<N_SBLK, 256, 0, stream>>>(cursorA, partialsA);
    k_scan_small<<<1, 128, 0, stream>>>(partialsA);
    k_scan_apply<<<N_SBLK, 256, 0, stream>>>(cursorA, row_startA, partialsA);
    k_scatter_rank<<<EBLK, 256, 0, stream>>>(esrc, edst, ew, a3,
                                             row_startA, rank, col_w);

    k_pull4<1, 1><<<PBLK, 256, 0, stream>>>(
        (const ushort8v*)xa0, row_startA, col_w, biasA, labels, a1, a2, a4,
        nullptr, (ushort8v*)xa1);
    k_pull4<0, 1><<<PBLK, 256, 0, stream>>>(
        (const ushort8v*)xa1, row_startA, col_w, biasA, labels, a1, a2, a4,
        nullptr, (ushort8v*)xa0);
    k_pull4<0, 1><<<PBLK, 256, 0, stream>>>(
        (const ushort8v*)xa0, row_startA, col_w, biasA, labels, a1, a2, a4,
        nullptr, (ushort8v*)xa1);
    k_pull4<0, 0><<<PBLK, 256, 0, stream>>>(
        (const ushort8v*)xa1, row_startA, col_w, biasA, labels, a1, a2, a4,
        (float4*)out, nullptr);
  } else if (ws_size >= need_B) {
    // ---- tier B: round-8 path (proven) ----
    k_cvt<<<CBLK, 256, 0, stream>>>((const float4*)x0, xb0);
    hipMemsetAsync(cursorB, 0, (size_t)N_NODES * 4, stream);
    k_hist<<<EBLK, 256, 0, stream>>>(edst, cursorB);
    k_partial<<<N_SBLK, 256, 0, stream>>>(cursorB, partialsB);
    k_scan_small<<<1, 128, 0, stream>>>(partialsB);
    k_scan_apply<<<N_SBLK, 256, 0, stream>>>(cursorB, row_startB, partialsB);
    k_sort<<<EBLK, 256, 0, stream>>>(esrc, edst, ew, a3, cursorB, colB, wsortedB);
    k_bias_csr<<<NBLK, 256, 0, stream>>>(row_startB, wsortedB, labels, a2, a4, biasB);

    k_pull<1><<<PBLK, 256, 0, stream>>>(xb0, row_startB, colB, biasB, a1, nullptr, xb1);
    k_pull<1><<<PBLK, 256, 0, stream>>>(xb1, row_startB, colB, biasB, a1, nullptr, xb0);
    k_pull<1><<<PBLK, 256, 0, stream>>>(xb0, row_startB, colB, biasB, a1, nullptr, xb1);
    k_pull<0><<<PBLK, 256, 0, stream>>>(xb1, row_startB, colB, biasB, a1, (float4*)out, nullptr);
  } else {
    // ---- tier C: atomic push fallback ----
    float* neigh  = (float*)ws;
    float* esums  = (float*)(ws + (size_t)N_NODES * D * 4);
    float* fbias  = esums + N_NODES;
    hipMemsetAsync(esums, 0, N_NODES * 4, stream);
    k_hist_legacy<<<EBLK, 256, 0, stream>>>(ew, edst, a3, esums);
    k_bias_only<<<NBLK, 256, 0, stream>>>(esums, labels, a2, a4, fbias);
    const float* xin = x0;
    for (int it = 0; it < 4; ++it) {
      hipMemsetAsync(neigh, 0, (size_t)N_NODES * D * 4, stream);
      long long tt = (long long)N_EDGES * 64;
      k_scatter<<<(int)(tt / 256), 256, 0, stream>>>(xin, esrc, edst, neigh);
      k_relu<<<CBLK, 256, 0, stream>>>((const float4*)neigh, fbias, a1, (float4*)out);
      xin = out;
    }
  }
}

// Round 12
// 574.926 us; speedup vs baseline: 5.3418x; 1.1742x over previous
//
#include <hip/hip_runtime.h>

constexpr int N_NODES = 100000;
constexpr int N_EDGES = 3200000;
constexpr int D = 64;
// ---- bucketed CSR build params ----
constexpr int BSH = 9;                               // 512-node buckets
constexpr int BSZ = 1 << BSH;
constexpr int NB  = (N_NODES + BSZ - 1) / BSZ;       // 196
constexpr int HCH = 4096;                            // edges per hist block
constexpr int HB  = (N_EDGES + HCH - 1) / HCH;       // 782
constexpr int PCH = 8192;                            // edges per partition block
constexpr int PB  = (N_EDGES + PCH - 1) / PCH;       // 391
// ---- legacy params (tier B/C) ----
constexpr int SCAN_CHUNK = 1024;
constexpr int N_SBLK = (N_NODES + SCAN_CHUNK - 1) / SCAN_CHUNK;  // 98
constexpr int EBLK = (N_EDGES + 255) / 256;                      // 12500
constexpr int CBLK = (N_NODES * (D / 4) + 255) / 256;            // 6250

typedef unsigned short ushort8v __attribute__((ext_vector_type(8)));

// ---------- bf16 helpers (manual RNE; no NaN/Inf in this workload) ----------
__device__ __forceinline__ float bf2f(unsigned short u) {
  union { unsigned int i; float f; } c; c.i = ((unsigned int)u) << 16; return c.f;
}
__device__ __forceinline__ unsigned short f2bf(float f) {
  union { float f; unsigned int i; } c; c.f = f;
  unsigned int b = c.i;
  return (unsigned short)((b + 0x7FFFu + ((b >> 16) & 1u)) >> 16);
}

// ==================== tier A: bucketed CSR build ========================

// Per-block LDS histogram of dst>>BSH (blocks 0..HB) + f32->bf16 cvt (rest).
__global__ __launch_bounds__(256) void k_bucket_hist_cvt(
    const int* __restrict__ dst, int* __restrict__ gcnt,
    const float4* __restrict__ xin, ushort4* __restrict__ xout) {
  int blk = blockIdx.x;
  int t = threadIdx.x;
  if (blk < HB) {
    __shared__ int cnt[256];
    cnt[t] = 0;
    __syncthreads();
    int base = blk * HCH;
#pragma unroll
    for (int k = 0; k < HCH / 256; ++k) {
      int e = base + k * 256 + t;
      if (e < N_EDGES) atomicAdd(&cnt[dst[e] >> BSH], 1);
    }
    __syncthreads();
    if (t < NB && cnt[t] > 0) atomicAdd(&gcnt[t], cnt[t]);
  } else {
    int i = (blk - HB) * 256 + t;
    if (i < N_NODES * (D / 4)) {
      float4 v = xin[i];
      ushort4 r;
      r.x = f2bf(v.x); r.y = f2bf(v.y); r.z = f2bf(v.z); r.w = f2bf(v.w);
      xout[i] = r;
    }
  }
}

// Exclusive scan of the NB bucket counts -> bbase. Also row_start[N]=E.
__global__ __launch_bounds__(256) void k_bucket_scan(
    const int* __restrict__ gcnt, int* __restrict__ bbase,
    int* __restrict__ row_start) {
  __shared__ int sh[256];
  int t = threadIdx.x;
  int v = (t < NB) ? gcnt[t] : 0;
  sh[t] = v;
  __syncthreads();
  for (int off = 1; off < 256; off <<= 1) {
    int u = (t >= off) ? sh[t - off] : 0;
    __syncthreads();
    sh[t] += u;
    __syncthreads();
  }
  if (t < NB) bbase[t] = sh[t] - v;  // exclusive
  if (t == 0) row_start[N_NODES] = N_EDGES;
}

// Partition edges into dst-buckets. Records: {src, (dstlow<<16)|w_bf16}.
// LDS-atomic local rank + one global atomic per (subchunk, bucket).
__global__ __launch_bounds__(256) void k_partition(
    const int* __restrict__ src, const int* __restrict__ dst,
    const float* __restrict__ ew, const float* __restrict__ a3,
    const int* __restrict__ bbase, int* __restrict__ g_cursor,
    uint2* __restrict__ part) {
  __shared__ uint2 stage[2048];
  __shared__ unsigned int meta[2048];   // b<<16 | lrank  (sentinel 0xFFFFFFFF)
  __shared__ int cnt[256];
  __shared__ int resv[256];
  const int t = threadIdx.x;
  const float a3v = a3[0];
  const int chunk0 = blockIdx.x * PCH;
  for (int sc = 0; sc < PCH / 2048; ++sc) {
    int base = chunk0 + sc * 2048;
    cnt[t] = 0;
    __syncthreads();
#pragma unroll
    for (int k = 0; k < 8; ++k) {
      int i = k * 256 + t;
      int e = base + i;
      if (e < N_EDGES) {
        int d = dst[e];
        int b = d >> BSH;
        int lrank = atomicAdd(&cnt[b], 1);
        unsigned short wb = f2bf(fmaxf(a3v * ew[e], 0.0f));
        uint2 rec;
        rec.x = (unsigned int)src[e];
        rec.y = ((unsigned int)(d & (BSZ - 1)) << 16) | (unsigned int)wb;
        stage[i] = rec;
        meta[i] = ((unsigned int)b << 16) | (unsigned int)lrank;
      } else {
        meta[i] = 0xFFFFFFFFu;
      }
    }
    __syncthreads();
    if (t < NB) {
      int c = cnt[t];
      resv[t] = (c > 0) ? atomicAdd(&g_cursor[t], c) : 0;
    }
    __syncthreads();
#pragma unroll
    for (int k = 0; k < 8; ++k) {
      int i = k * 256 + t;
      unsigned int m = meta[i];
      if (m != 0xFFFFFFFFu) {
        int b = (int)(m >> 16);
        int lr = (int)(m & 0xFFFFu);
        part[bbase[b] + resv[b] + lr] = stage[i];
      }
    }
    __syncthreads();
  }
}

// Per-bucket CSR: LDS hist + scan + LDS-atomic rank. Emits row_start, bias,
// and compact 4B col. All heavy ops are LDS; writes are bucket-local.
__global__ __launch_bounds__(256) void k_bucket_csr(
    const uint2* __restrict__ part,
    const int* __restrict__ bbase, const int* __restrict__ gcnt,
    const int* __restrict__ labels,
    const float* __restrict__ a2, const float* __restrict__ a4,
    int* __restrict__ row_start, float* __restrict__ bias,
    int* __restrict__ col) {
  __shared__ int hist[BSZ];        // counts, then reused as rank cursors
  __shared__ int rsl[BSZ];         // bucket-local exclusive row starts
  __shared__ float bacc[BSZ];      // per-node sum of relu(a3*w)
  __shared__ int ps[256];          // pair-scan workspace
  const int b = blockIdx.x;
  const int t = threadIdx.x;
  const int nbase = b << BSH;
  const int ncnt = min(BSZ, N_NODES - nbase);
  const int ebase = bbase[b];
  const int ecnt = gcnt[b];

  hist[t] = 0; hist[t + 256] = 0;
  bacc[t] = 0.f; bacc[t + 256] = 0.f;
  __syncthreads();
  // sweep 1: histogram + bias accumulation
  for (int i = t; i < ecnt; i += 256) {
    uint2 rec = part[ebase + i];
    int dl = (int)(rec.y >> 16);
    atomicAdd(&hist[dl], 1);
    atomicAdd(&bacc[dl], bf2f((unsigned short)(rec.y & 0xFFFFu)));
  }
  __syncthreads();
  // scan of 512 via 256-thread pair scan
  int s0 = hist[2 * t], s1 = hist[2 * t + 1];
  int pair = s0 + s1;
  ps[t] = pair;
  __syncthreads();
  for (int off = 1; off < 256; off <<= 1) {
    int u = (t >= off) ? ps[t - off] : 0;
    __syncthreads();
    ps[t] += u;
    __syncthreads();
  }
  int excl = ps[t] - pair;
  rsl[2 * t] = excl;
  rsl[2 * t + 1] = excl + s0;
  __syncthreads();
  // emit row_start + bias; reset cursors
  float a2v = a2[0], a4v = a4[0];
  for (int j = t; j < ncnt; j += 256) {
    row_start[nbase + j] = ebase + rsl[j];
    bias[nbase + j] = a2v * bacc[j] + a4v * (float)labels[nbase + j];
  }
  hist[t] = 0; hist[t + 256] = 0;
  __syncthreads();
  // sweep 2: rank + compact col write (bucket-local region)
  for (int i = t; i < ecnt; i += 256) {
    uint2 rec = part[ebase + i];
    int dl = (int)(rec.y >> 16);
    int r = atomicAdd(&hist[dl], 1);
    col[ebase + rsl[dl] + r] = (int)rec.x;
  }
}

// ====================== pull iteration (no atomics) =====================
// One wave per node; 8 edge slots x 8 lanes x 16B; 4-deep mask-guarded MLP.
template <int WRITE_BF16>
__global__ __launch_bounds__(256) void k_pull5(
    const ushort8v* __restrict__ x,
    const int* __restrict__ row_start,
    const int* __restrict__ col,
    const float* __restrict__ bias,
    const float* __restrict__ a1,
    float4* __restrict__ outf, ushort8v* __restrict__ outb) {
  int node = (blockIdx.x * 256 + threadIdx.x) >> 6;
  if (node >= N_NODES) return;
  int lane = threadIdx.x & 63;
  int slot = lane >> 3;   // 0..7: edge slot
  int l8 = lane & 7;      // 16B chunk of the 128B row
  int beg = row_start[node], end = row_start[node + 1];
  float acc[8] = {0.f, 0.f, 0.f, 0.f, 0.f, 0.f, 0.f, 0.f};
  int jm = end - 1;
  for (int j = beg + slot; j < end; j += 32) {
    int j1 = j + 8, j2 = j + 16, j3 = j + 24;
    float m1 = (j1 < end) ? 1.f : 0.f;
    float m2 = (j2 < end) ? 1.f : 0.f;
    float m3 = (j3 < end) ? 1.f : 0.f;
    j1 = (j1 < end) ? j1 : jm;
    j2 = (j2 < end) ? j2 : jm;
    j3 = (j3 < end) ? j3 : jm;
    int c0 = col[j];
    int c1 = col[j1];
    int c2 = col[j2];
    int c3 = col[j3];
    ushort8v v0 = x[c0 * 8 + l8];
    ushort8v v1 = x[c1 * 8 + l8];
    ushort8v v2 = x[c2 * 8 + l8];
    ushort8v v3 = x[c3 * 8 + l8];
#pragma unroll
    for (int k = 0; k < 8; ++k) {
      acc[k] += bf2f(v0[k]);
      acc[k] = fmaf(m1, bf2f(v1[k]), acc[k]);
      acc[k] = fmaf(m2, bf2f(v2[k]), acc[k]);
      acc[k] = fmaf(m3, bf2f(v3[k]), acc[k]);
    }
  }
#pragma unroll
  for (int k = 0; k < 8; ++k) {
    acc[k] += __shfl_xor(acc[k], 8);
    acc[k] += __shfl_xor(acc[k], 16);
    acc[k] += __shfl_xor(acc[k], 32);
  }
  if (slot == 0) {
    float al = a1[0], bb = bias[node];
#pragma unroll
    for (int k = 0; k < 8; ++k) acc[k] = fmaxf(fmaf(al, acc[k], bb), 0.f);
    if (WRITE_BF16) {
      ushort8v r;
#pragma unroll
      for (int k = 0; k < 8; ++k) r[k] = f2bf(acc[k]);
      outb[node * 8 + l8] = r;
    } else {
      float4 r0, r1;
      r0.x = acc[0]; r0.y = acc[1]; r0.z = acc[2]; r0.w = acc[3];
      r1.x = acc[4]; r1.y = acc[5]; r1.z = acc[6]; r1.w = acc[7];
      outf[node * 16 + l8 * 2] = r0;
      outf[node * 16 + l8 * 2 + 1] = r1;
    }
  }
}

// =================== tier-B kernels (round-8 CSR path) ==================

__global__ __launch_bounds__(256) void k_cvt(
    const float4* __restrict__ xin, ushort4* __restrict__ xout) {
  int t = blockIdx.x * 256 + threadIdx.x;
  if (t >= N_NODES * (D / 4)) return;
  float4 v = xin[t];
  ushort4 r;
  r.x = f2bf(v.x); r.y = f2bf(v.y); r.z = f2bf(v.z); r.w = f2bf(v.w);
  xout[t] = r;
}

__global__ __launch_bounds__(256) void k_hist(
    const int* __restrict__ dst, int* __restrict__ deg_cursor) {
  int e = blockIdx.x * 256 + threadIdx.x;
  if (e >= N_EDGES) return;
  atomicAdd(&deg_cursor[dst[e]], 1);
}

__global__ __launch_bounds__(256) void k_partial(
    const int* __restrict__ deg, int* __restrict__ partials) {
  __shared__ int red[256];
  int t = threadIdx.x;
  int base = blockIdx.x * SCAN_CHUNK + t * 4;
  int s = 0;
#pragma unroll
  for (int k = 0; k < 4; ++k) {
    int i = base + k;
    if (i < N_NODES) s += deg[i];
  }
  red[t] = s;
  __syncthreads();
  for (int off = 128; off > 0; off >>= 1) {
    if (t < off) red[t] += red[t + off];
    __syncthreads();
  }
  if (t == 0) partials[blockIdx.x] = red[0];
}

__global__ __launch_bounds__(128) void k_scan_small(int* __restrict__ partials) {
  __shared__ int sh[128];
  int t = threadIdx.x;
  int v = (t < N_SBLK) ? partials[t] : 0;
  sh[t] = v;
  __syncthreads();
  for (int off = 1; off < 128; off <<= 1) {
    int u = (t >= off) ? sh[t - off] : 0;
    __syncthreads();
    sh[t] += u;
    __syncthreads();
  }
  if (t < N_SBLK) partials[t] = sh[t] - v;
}

__global__ __launch_bounds__(256) void k_scan_apply(
    int* __restrict__ deg_cursor, int* __restrict__ row_start,
    const int* __restrict__ partials) {
  __shared__ int sh[256];
  int b = blockIdx.x, t = threadIdx.x;
  int base = b * SCAN_CHUNK + t * 4;
  int d[4];
  int s = 0;
#pragma unroll
  for (int k = 0; k < 4; ++k) {
    int i = base + k;
    d[k] = (i < N_NODES) ? deg_cursor[i] : 0;
    s += d[k];
  }
  sh[t] = s;
  __syncthreads();
  for (int off = 1; off < 256; off <<= 1) {
    int u = (t >= off) ? sh[t - off] : 0;
    __syncthreads();
    sh[t] += u;
    __syncthreads();
  }
  int run = partials[b] + sh[t] - s;
#pragma unroll
  for (int k = 0; k < 4; ++k) {
    int i = base + k;
    if (i < N_NODES) {
      row_start[i] = run;
      deg_cursor[i] = run;
      run += d[k];
    }
  }
  if (b == 0 && t == 0) row_start[N_NODES] = N_EDGES;
}

__global__ __launch_bounds__(256) void k_sort(
    const int* __restrict__ src, const int* __restrict__ dst,
    const float* __restrict__ ew, const float* __restrict__ a3,
    int* __restrict__ cursor, int* __restrict__ col,
    float* __restrict__ wsorted) {
  int e = blockIdx.x * 256 + threadIdx.x;
  if (e >= N_EDGES) return;
  int pos = atomicAdd(&cursor[dst[e]], 1);
  col[pos] = src[e];
  wsorted[pos] = fmaxf(a3[0] * ew[e], 0.0f);
}

__global__ __launch_bounds__(256) void k_bias_csr(
    const int* __restrict__ row_start, const float* __restrict__ wsorted,
    const int* __restrict__ labels,
    const float* __restrict__ a2, const float* __restrict__ a4,
    float* __restrict__ bias) {
  int n = blockIdx.x * 256 + threadIdx.x;
  if (n >= N_NODES) return;
  int beg = row_start[n], end = row_start[n + 1];
  float s = 0.f;
  for (int j = beg; j < end; ++j) s += wsorted[j];
  bias[n] = a2[0] * s + a4[0] * (float)labels[n];
}

template <int WRITE_BF16>
__global__ __launch_bounds__(256) void k_pull(
    const ushort4* __restrict__ x,
    const int* __restrict__ row_start,
    const int* __restrict__ col,
    const float* __restrict__ bias,
    const float* __restrict__ a1,
    float4* __restrict__ outf, ushort4* __restrict__ outb) {
  int node = (blockIdx.x * 256 + threadIdx.x) >> 6;
  if (node >= N_NODES) return;
  int lane = threadIdx.x & 63;
  int sub = lane >> 4;
  int l16 = lane & 15;
  int beg = row_start[node], end = row_start[node + 1];
  float ax = 0.f, ay = 0.f, az = 0.f, aw = 0.f;
  for (int j = beg + sub; j < end; j += 4) {
    int s = col[j];
    ushort4 v = x[s * 16 + l16];
    ax += bf2f(v.x); ay += bf2f(v.y); az += bf2f(v.z); aw += bf2f(v.w);
  }
  ax += __shfl_xor(ax, 16); ay += __shfl_xor(ay, 16);
  az += __shfl_xor(az, 16); aw += __shfl_xor(aw, 16);
  ax += __shfl_xor(ax, 32); ay += __shfl_xor(ay, 32);
  az += __shfl_xor(az, 32); aw += __shfl_xor(aw, 32);
  if (sub == 0) {
    float al = a1[0], b = bias[node];
    float rx = fmaxf(fmaf(al, ax, b), 0.f);
    float ry = fmaxf(fmaf(al, ay, b), 0.f);
    float rz = fmaxf(fmaf(al, az, b), 0.f);
    float rw = fmaxf(fmaf(al, aw, b), 0.f);
    if (WRITE_BF16) {
      ushort4 r;
      r.x = f2bf(rx); r.y = f2bf(ry); r.z = f2bf(rz); r.w = f2bf(rw);
      outb[node * 16 + l16] = r;
    } else {
      float4 r; r.x = rx; r.y = ry; r.z = rz; r.w = rw;
      outf[node * 16 + l16] = r;
    }
  }
}

// ===================== fallback (atomic push path) ======================

__global__ __launch_bounds__(256) void k_hist_legacy(
    const float* __restrict__ ew, const int* __restrict__ dst,
    const float* __restrict__ a3, float* __restrict__ edge_sums) {
  int e = blockIdx.x * 256 + threadIdx.x;
  if (e >= N_EDGES) return;
  atomicAdd(&edge_sums[dst[e]], fmaxf(a3[0] * ew[e], 0.0f));
}

__global__ __launch_bounds__(256) void k_bias_only(
    const float* __restrict__ edge_sums, const int* __restrict__ labels,
    const float* __restrict__ a2, const float* __restrict__ a4,
    float* __restrict__ bias) {
  int n = blockIdx.x * 256 + threadIdx.x;
  if (n >= N_NODES) return;
  bias[n] = a2[0] * edge_sums[n] + a4[0] * (float)labels[n];
}

__global__ __launch_bounds__(256) void k_scatter(
    const float* __restrict__ x, const int* __restrict__ src,
    const int* __restrict__ dst, float* __restrict__ neigh) {
  long long t = (long long)blockIdx.x * 256 + threadIdx.x;
  int e = (int)(t >> 6);
  int lane = (int)(t & 63);
  if (e >= N_EDGES) return;
  atomicAdd(&neigh[dst[e] * D + lane], x[src[e] * D + lane]);
}

__global__ __launch_bounds__(256) void k_relu(
    const float4* __restrict__ neigh, const float* __restrict__ bias,
    const float* __restrict__ a1, float4* __restrict__ xout) {
  int t = blockIdx.x * 256 + threadIdx.x;
  if (t >= N_NODES * (D / 4)) return;
  int n = t >> 4;
  float al = a1[0], b = bias[n];
  float4 v = neigh[t];
  float4 r;
  r.x = fmaxf(al * v.x + b, 0.f);
  r.y = fmaxf(al * v.y + b, 0.f);
  r.z = fmaxf(al * v.z + b, 0.f);
  r.w = fmaxf(al * v.w + b, 0.f);
  xout[t] = r;
}

// ============================== launch ==================================

extern "C" void kernel_launch(void* const* d_in, const int* in_sizes, int n_in,
                              void* d_out, int out_size, void* d_ws, size_t ws_size,
                              hipStream_t stream) {
  const float* x0     = (const float*)d_in[0];
  const float* ew     = (const float*)d_in[1];
  const float* a1     = (const float*)d_in[2];
  const float* a2     = (const float*)d_in[3];
  const float* a3     = (const float*)d_in[4];
  const float* a4     = (const float*)d_in[5];
  const int*   esrc   = (const int*)d_in[6];
  const int*   edst   = (const int*)d_in[7];
  const int*   labels = (const int*)d_in[8];
  float* out = (float*)d_out;

  char* ws = (char*)d_ws;
  const int PBLK = (N_NODES * 64 + 255) / 256;
  const int NBLK = (N_NODES + 255) / 256;

  // ---------------- tier A layout (~52.0 MB) ----------------
  size_t offA = 0;
  int*   gcnt      = (int*)(ws + offA);   offA += 256 * 4;
  int*   bbase     = (int*)(ws + offA);   offA += 256 * 4;
  int*   g_cursor  = (int*)(ws + offA);   offA += 256 * 4;
  int*   row_startA = (int*)(ws + offA);  offA += (size_t)(N_NODES + 4) * 4;
  float* biasA     = (float*)(ws + offA); offA += (size_t)N_NODES * 4;
  int*   colA      = (int*)(ws + offA);   offA += (size_t)N_EDGES * 4;      // 12.8M
  ushort4* xa0     = (ushort4*)(ws + offA); offA += (size_t)N_NODES * D * 2; // 12.8M
  // part (E*8 = 25.6MB); xa1 aliases its first 12.8MB (part dead after
  // k_bucket_csr; xa1 first written by pull #1 — stream-ordered).
  char* aliasA     = ws + offA;           offA += (size_t)N_EDGES * 8;
  uint2*   part    = (uint2*)aliasA;
  ushort4* xa1     = (ushort4*)aliasA;
  const size_t need_A = offA;

  // ---------------- tier B layout (~39.8 MB, round-8) ----------------
  size_t offB = 0;
  int*   cursorB    = (int*)(ws + offB);   offB += (size_t)N_NODES * 4;
  int*   row_startB = (int*)(ws + offB);   offB += (size_t)(N_NODES + 4) * 4;
  float* biasB      = (float*)(ws + offB); offB += (size_t)N_NODES * 4;
  int*   partialsB  = (int*)(ws + offB);   offB += 128 * 4;
  int*   colB       = (int*)(ws + offB);   offB += (size_t)N_EDGES * 4;
  ushort4* xb0      = (ushort4*)(ws + offB); offB += (size_t)N_NODES * D * 2;
  char* aliasB      = ws + offB;           offB += (size_t)N_EDGES * 4;
  float*   wsortedB = (float*)aliasB;
  ushort4* xb1      = (ushort4*)aliasB;
  const size_t need_B = offB;

  if (ws_size >= need_A) {
    // ---- tier A: bucketed CSR build + compact-col pulls ----
    hipMemsetAsync(gcnt, 0, 3 * 256 * 4, stream);  // gcnt, bbase, g_cursor
    k_bucket_hist_cvt<<<HB + CBLK, 256, 0, stream>>>(
        edst, gcnt, (const float4*)x0, xa0);
    k_bucket_scan<<<1, 256, 0, stream>>>(gcnt, bbase, row_startA);
    k_partition<<<PB, 256, 0, stream>>>(esrc, edst, ew, a3, bbase, g_cursor, part);
    k_bucket_csr<<<NB, 256, 0, stream>>>(part, bbase, gcnt, labels, a2, a4,
                                         row_startA, biasA, colA);

    k_pull5<1><<<PBLK, 256, 0, stream>>>((const ushort8v*)xa0, row_startA, colA,
                                         biasA, a1, nullptr, (ushort8v*)xa1);
    k_pull5<1><<<PBLK, 256, 0, stream>>>((const ushort8v*)xa1, row_startA, colA,
                                         biasA, a1, nullptr, (ushort8v*)xa0);
    k_pull5<1><<<PBLK, 256, 0, stream>>>((const ushort8v*)xa0, row_startA, colA,
                                         biasA, a1, nullptr, (ushort8v*)xa1);
    k_pull5<0><<<PBLK, 256, 0, stream>>>((const ushort8v*)xa1, row_startA, colA,
                                         biasA, a1, (float4*)out, nullptr);
  } else if (ws_size >= need_B) {
    // ---- tier B: round-8 path (proven) ----
    k_cvt<<<CBLK, 256, 0, stream>>>((const float4*)x0, xb0);
    hipMemsetAsync(cursorB, 0, (size_t)N_NODES * 4, stream);
    k_hist<<<EBLK, 256, 0, stream>>>(edst, cursorB);
    k_partial<<<N_SBLK, 256, 0, stream>>>(cursorB, partialsB);
    k_scan_small<<<1, 128, 0, stream>>>(partialsB);
    k_scan_apply<<<N_SBLK, 256, 0, stream>>>(cursorB, row_startB, partialsB);
    k_sort<<<EBLK, 256, 0, stream>>>(esrc, edst, ew, a3, cursorB, colB, wsortedB);
    k_bias_csr<<<NBLK, 256, 0, stream>>>(row_startB, wsortedB, labels, a2, a4, biasB);

    k_pull<1><<<PBLK, 256, 0, stream>>>(xb0, row_startB, colB, biasB, a1, nullptr, xb1);
    k_pull<1><<<PBLK, 256, 0, stream>>>(xb1, row_startB, colB, biasB, a1, nullptr, xb0);
    k_pull<1><<<PBLK, 256, 0, stream>>>(xb0, row_startB, colB, biasB, a1, nullptr, xb1);
    k_pull<0><<<PBLK, 256, 0, stream>>>(xb1, row_startB, colB, biasB, a1, (float4*)out, nullptr);
  } else {
    // ---- tier C: atomic push fallback ----
    float* neigh  = (float*)ws;
    float* esums  = (float*)(ws + (size_t)N_NODES * D * 4);
    float* fbias  = esums + N_NODES;
    hipMemsetAsync(esums, 0, N_NODES * 4, stream);
    k_hist_legacy<<<EBLK, 256, 0, stream>>>(ew, edst, a3, esums);
    k_bias_only<<<NBLK, 256, 0, stream>>>(esums, labels, a2, a4, fbias);
    const float* xin = x0;
    for (int it = 0; it < 4; ++it) {
      hipMemsetAsync(neigh, 0, (size_t)N_NODES * D * 4, stream);
      long long tt = (long long)N_EDGES * 64;
      k_scatter<<<(int)(tt / 256), 256, 0, stream>>>(xin, esrc, edst, neigh);
      k_relu<<<CBLK, 256, 0, stream>>>((const float4*)neigh, fbias, a1, (float4*)out);
      xin = out;
    }
  }
}